// Round 11
// baseline (35962.988 us; speedup 1.0000x reference)
//
#include <hip/hip_runtime.h>
#include <hip/hip_bf16.h>
#include <stdint.h>

// Problem dims
#define Bn 128
#define Tn 512
#define En 512
#define Hn 2048
#define Vn 32000
#define R0 8
#define R1 4
#define HSLOT (Bn*Hn)

// flags: reps r*1024 (+0 fA0[16], +64 fB0[16]); FPA/FPB private lines
#define NREP 8
#define FPA 8192       // + (g*8+s)*16
#define FPB 10240      // + (g*8+s)*16
#define FLAG_WORDS 16384
#define BAILLIM 16384

typedef float f32x4 __attribute__((ext_vector_type(4)));
typedef short bf16x8 __attribute__((ext_vector_type(8)));
typedef unsigned long long u64;

__device__ __forceinline__ unsigned short f2b(float f) {
  uint32_t x = __builtin_bit_cast(uint32_t, f);
  uint32_t r = x + 0x7FFFu + ((x >> 16) & 1u);
  return (unsigned short)(r >> 16);
}

// MALL ops (r2-r9 proven)
__device__ __forceinline__ uint32_t ldf(const uint32_t* p) {
  return __hip_atomic_load(p, __ATOMIC_RELAXED, __HIP_MEMORY_SCOPE_AGENT);
}
__device__ __forceinline__ void stf(uint32_t* p, uint32_t v) {
  __hip_atomic_store(p, v, __ATOMIC_RELAXED, __HIP_MEMORY_SCOPE_AGENT);
}
__device__ __forceinline__ void st64(u64* p, u64 v) {
  __hip_atomic_store(p, v, __ATOMIC_RELAXED, __HIP_MEMORY_SCOPE_AGENT);
}
union F32x4u { f32x4 v; u64 q[2]; };
__device__ __forceinline__ void st_p(float* p, f32x4 x) {
  F32x4u u; u.v = x;
  st64((u64*)p, u.q[0]); st64((u64*)p + 1, u.q[1]);
}
__device__ __forceinline__ void drain_then_sync() {
  asm volatile("s_waitcnt vmcnt(0)" ::: "memory");
  __syncthreads();
}

// 16-deep MALL-coherent loads (sc0 sc1 — r7-proven) for h reads: 8 kt-tiles x 2 rows
#define LD16_MALL(PA, PB) \
  asm volatile( \
      "global_load_dwordx4 %[t0], %[a], off sc0 sc1\n\t" \
      "global_load_dwordx4 %[t1], %[a], off offset:64 sc0 sc1\n\t" \
      "global_load_dwordx4 %[t2], %[a], off offset:128 sc0 sc1\n\t" \
      "global_load_dwordx4 %[t3], %[a], off offset:192 sc0 sc1\n\t" \
      "global_load_dwordx4 %[t4], %[a], off offset:256 sc0 sc1\n\t" \
      "global_load_dwordx4 %[t5], %[a], off offset:320 sc0 sc1\n\t" \
      "global_load_dwordx4 %[t6], %[a], off offset:384 sc0 sc1\n\t" \
      "global_load_dwordx4 %[t7], %[a], off offset:448 sc0 sc1\n\t" \
      "global_load_dwordx4 %[t8], %[b], off sc0 sc1\n\t" \
      "global_load_dwordx4 %[t9], %[b], off offset:64 sc0 sc1\n\t" \
      "global_load_dwordx4 %[ta], %[b], off offset:128 sc0 sc1\n\t" \
      "global_load_dwordx4 %[tb], %[b], off offset:192 sc0 sc1\n\t" \
      "global_load_dwordx4 %[tc], %[b], off offset:256 sc0 sc1\n\t" \
      "global_load_dwordx4 %[td], %[b], off offset:320 sc0 sc1\n\t" \
      "global_load_dwordx4 %[te], %[b], off offset:384 sc0 sc1\n\t" \
      "global_load_dwordx4 %[tf], %[b], off offset:448 sc0 sc1\n\t" \
      "s_waitcnt vmcnt(0)" \
      : [t0]"=&v"(v0), [t1]"=&v"(v1), [t2]"=&v"(v2), [t3]"=&v"(v3), \
        [t4]"=&v"(v4), [t5]"=&v"(v5), [t6]"=&v"(v6), [t7]"=&v"(v7), \
        [t8]"=&v"(v8), [t9]"=&v"(v9), [ta]"=&v"(va), [tb]"=&v"(vb), \
        [tc]"=&v"(vc), [td]"=&v"(vd), [te]"=&v"(ve), [tf]"=&v"(vf) \
      : [a]"v"(PA), [b]"v"(PB) : "memory"); \
  __builtin_amdgcn_sched_barrier(0)

// 16-deep partial fetch: per-THREAD-major layout (tid*64 floats), single drain
#define LD16P(BASE) \
  asm volatile( \
      "global_load_dwordx4 %[t0], %[a], off sc0 sc1\n\t" \
      "global_load_dwordx4 %[t1], %[a], off offset:16 sc0 sc1\n\t" \
      "global_load_dwordx4 %[t2], %[a], off offset:32 sc0 sc1\n\t" \
      "global_load_dwordx4 %[t3], %[a], off offset:48 sc0 sc1\n\t" \
      "global_load_dwordx4 %[t4], %[a], off offset:64 sc0 sc1\n\t" \
      "global_load_dwordx4 %[t5], %[a], off offset:80 sc0 sc1\n\t" \
      "global_load_dwordx4 %[t6], %[a], off offset:96 sc0 sc1\n\t" \
      "global_load_dwordx4 %[t7], %[a], off offset:112 sc0 sc1\n\t" \
      "global_load_dwordx4 %[t8], %[a], off offset:128 sc0 sc1\n\t" \
      "global_load_dwordx4 %[t9], %[a], off offset:144 sc0 sc1\n\t" \
      "global_load_dwordx4 %[ta], %[a], off offset:160 sc0 sc1\n\t" \
      "global_load_dwordx4 %[tb], %[a], off offset:176 sc0 sc1\n\t" \
      "global_load_dwordx4 %[tc], %[a], off offset:192 sc0 sc1\n\t" \
      "global_load_dwordx4 %[td], %[a], off offset:208 sc0 sc1\n\t" \
      "global_load_dwordx4 %[te], %[a], off offset:224 sc0 sc1\n\t" \
      "global_load_dwordx4 %[tf], %[a], off offset:240 sc0 sc1\n\t" \
      "s_waitcnt vmcnt(0)" \
      : [t0]"=&v"(q0), [t1]"=&v"(q1), [t2]"=&v"(q2), [t3]"=&v"(q3), \
        [t4]"=&v"(q4), [t5]"=&v"(q5), [t6]"=&v"(q6), [t7]"=&v"(q7), \
        [t8]"=&v"(q8), [t9]"=&v"(q9), [ta]"=&v"(qa), [tb]"=&v"(qb), \
        [tc]"=&v"(qc), [td]"=&v"(qd), [te]"=&v"(qe), [tf]"=&v"(qf) \
      : [a]"v"(BASE) : "memory"); \
  __builtin_amdgcn_sched_barrier(0)

// ---------------- init / pack kernels ----------------

__global__ void zero3(uint32_t* a, int na, uint32_t* b, int nb, uint32_t* c, int nc) {
  int i = blockIdx.x * 256 + threadIdx.x;
  if (i < na) a[i] = 0u;
  if (i < nb) b[i] = 0u;
  if (i < nc) c[i] = 0u;
}

__global__ void pack_bias(const float* bih0, const float* bhh0,
                          const float* bih1, const float* bhh1,
                          float* bias0, float* bias1) {
  int i = blockIdx.x * 256 + threadIdx.x;
  bias0[i] = bih0[i] + bhh0[i];
  bias1[i] = bih1[i] + bhh1[i];
}

// 16 groups x 128 cols, nseg K-segments of 512. packet p=(kt*8+ct)*64+l within
// (g,seg) slice of 8192 packets. lane l elem j: src[col=g*128+ct*16+(l&15)]
// [k = seg*512 + kt*32 + (l>>4)*8 + j], src row-major [2048 x Ksrc].
__global__ void pack_seg(const float* __restrict__ src, int Ksrc, int nseg,
                         uint4* __restrict__ img) {
  int tid = blockIdx.x * 256 + threadIdx.x;
  int per = nseg * 8192;
  int g = tid / per, r1 = tid - g * per;
  int seg = r1 >> 13, p = r1 & 8191;
  int kt = p >> 9, ct = (p >> 6) & 7, l = p & 63;
  int col = g * 128 + ct * 16 + (l & 15);
  int k = seg * 512 + kt * 32 + (l >> 4) * 8;
  const float* s = src + (size_t)col * Ksrc + k;
  unsigned short o[8];
#pragma unroll
  for (int j = 0; j < 8; ++j) o[j] = f2b(s[j]);
  img[tid] = *reinterpret_cast<uint4*>(o);
}

__global__ void pack_imgW1(const float* __restrict__ W1, uint4* __restrict__ img) {
  int tid = blockIdx.x * 256 + threadIdx.x;
  int grp = tid >> 12;
  int p = tid & 4095;
  int l = p & 63;
  int kt = p >> 6;
  int col = grp * 16 + (l & 15);
  int k0 = kt * 32 + (l >> 4) * 8;
  const float* src = W1 + (size_t)col * Hn + k0;
  unsigned short o[8];
#pragma unroll
  for (int j = 0; j < 8; ++j) o[j] = f2b(src[j]);
  img[tid] = *reinterpret_cast<uint4*>(o);
}

__global__ void pack_imgW2(const float* __restrict__ W2, uint4* __restrict__ img) {
  int tid = blockIdx.x * 256 + threadIdx.x;
  int grp = tid >> 12;
  int p = tid & 4095;
  int l = p & 63;
  int ckt = p >> 6;
  int ct = ckt & 3, kt = ckt >> 2;
  int col = grp * 64 + ct * 16 + (l & 15);
  int k0 = kt * 32 + (l >> 4) * 8;
  const float* src = W2 + (size_t)col * En + k0;
  unsigned short o[8];
#pragma unroll
  for (int j = 0; j < 8; ++j) o[j] = f2b(src[j]);
  img[tid] = *reinterpret_cast<uint4*>(o);
}

__global__ void gather_x(const int* __restrict__ ids, const float* __restrict__ emb,
                         uint4* __restrict__ xall) {
  int tid = blockIdx.x * 256 + threadIdx.x;
  int t = tid >> 13;
  int r = tid & 8191;
  int b = r >> 6;
  int e8 = r & 63;
  int id = ids[b * Tn + t];
  const float* src = emb + (size_t)id * En + e8 * 8;
  unsigned short o[8];
#pragma unroll
  for (int j = 0; j < 8; ++j) o[j] = f2b(src[j]);
  xall[tid] = *reinterpret_cast<uint4*>(o);
}

// ---------------- persistent RNN v13: v12 + pbuf index fix (tid*64, was l*64) ----
// 208 blocks x 256 thr, 1/CU. Roles by blockIdx (no XCD logic):
//  blk<80:  roleA, g=blk/5, s=blk%5. s0: Wih0.x_t. s1..4: Whh0 K-slice (s-1)*512
//           of h0[t-1]. s1 = reducer: + partials + bias0 -> tanh -> h0ring, fA0.
//  blk>=80: roleB, bb=blk-80, g=bb>>3, s=bb&7. s0..3: Wih1 slice s*512 of h0[t].
//           s4..7: Whh1 slice (s-4)*512 of h1[t-1]. s4 = reducer -> h1ring, fB0.
// Partials: f32, per-THREAD-major: slot*16384 + tid*64 floats (256 thr x 64 = 16384).
// v12 BUG (fixed): used l*64 (l=tid&63) -> 4 waves clobbered same quarter.

#define MFB8(KT, A0, A1) do { \
    bf16x8 bw_; \
    _Pragma("unroll") \
    for (int ct_ = 0; ct_ < 8; ++ct_) { \
      bw_ = wlds[((KT) * 8 + ct_) * 64 + l]; \
      acc[0][ct_] = __builtin_amdgcn_mfma_f32_16x16x32_bf16(A0, bw_, acc[0][ct_], 0, 0, 0); \
      acc[1][ct_] = __builtin_amdgcn_mfma_f32_16x16x32_bf16(A1, bw_, acc[1][ct_], 0, 0, 0); \
    } \
  } while (0)

// K=512 slice from BASE (row-major, stride STRIDE elements), MALL-coherent
#define KLOOP512(BASE, STRIDE) do { \
    const unsigned short* pr0_ = (BASE) + (size_t)row0 * (STRIDE) + kq * 8; \
    const unsigned short* pr1_ = pr0_ + (size_t)16 * (STRIDE); \
    _Pragma("unroll") \
    for (int b_ = 0; b_ < 2; ++b_) { \
      const unsigned short* pa_ = pr0_ + b_ * 256; \
      const unsigned short* pb_ = pr1_ + b_ * 256; \
      bf16x8 v0,v1,v2,v3,v4,v5,v6,v7,v8,v9,va,vb,vc,vd,ve,vf; \
      LD16_MALL(pa_, pb_); \
      const int kb_ = b_ * 8; \
      MFB8(kb_+0, v0, v8); MFB8(kb_+1, v1, v9); MFB8(kb_+2, v2, va); MFB8(kb_+3, v3, vb); \
      MFB8(kb_+4, v4, vc); MFB8(kb_+5, v5, vd); MFB8(kb_+6, v6, ve); MFB8(kb_+7, v7, vf); \
    } \
  } while (0)

#define ADD_PARTIAL(SRC) do { \
    f32x4 q0,q1,q2,q3,q4,q5,q6,q7,q8,q9,qa,qb,qc,qd,qe,qf; \
    const float* pb_ = (SRC) + (size_t)tid * 64; \
    LD16P(pb_); \
    acc[0][0]+=q0; acc[0][1]+=q1; acc[0][2]+=q2; acc[0][3]+=q3; \
    acc[0][4]+=q4; acc[0][5]+=q5; acc[0][6]+=q6; acc[0][7]+=q7; \
    acc[1][0]+=q8; acc[1][1]+=q9; acc[1][2]+=qa; acc[1][3]+=qb; \
    acc[1][4]+=qc; acc[1][5]+=qd; acc[1][6]+=qe; acc[1][7]+=qf; \
  } while (0)

__global__ __launch_bounds__(256, 1) void rnn_persist(
    const uint4* __restrict__ imgWih0, const uint4* __restrict__ imgWhh0,
    const uint4* __restrict__ imgWih1, const uint4* __restrict__ imgWhh1,
    const unsigned short* __restrict__ xall,
    unsigned short* __restrict__ h0ring, unsigned short* __restrict__ h1ring,
    float* __restrict__ pbufA, float* __restrict__ pbufB,
    const float* __restrict__ bias0, const float* __restrict__ bias1,
    uint32_t* flags) {
  __shared__ uint4 smem[8192];  // 128 KiB -> 1 block/CU, 208 blocks all resident
  const int tid = threadIdx.x;
  const int w = tid >> 6, l = tid & 63, l15 = l & 15, kq = l >> 4;
  const int blk = blockIdx.x;
  const bool roleA = (blk < 80);
  const int g = roleA ? (blk / 5) : ((blk - 80) >> 3);
  const int s = roleA ? (blk % 5) : ((blk - 80) & 7);
  const int myrep = blk & (NREP - 1);
  const uint32_t* fA0r = flags + (size_t)myrep * 1024;
  const uint32_t* fB0r = flags + (size_t)myrep * 1024 + 64;
  const int colbase = g * 128;

  {  // stage weights (128 KiB slice)
    const uint4* wsrc;
    if (roleA) wsrc = (s == 0) ? (imgWih0 + (size_t)g * 8192)
                               : (imgWhh0 + (size_t)(g * 4 + s - 1) * 8192);
    else       wsrc = (s < 4)  ? (imgWih1 + (size_t)(g * 4 + s) * 8192)
                               : (imgWhh1 + (size_t)(g * 4 + s - 4) * 8192);
    for (int i = tid; i < 8192; i += 256) smem[i] = wsrc[i];
  }
  __syncthreads();
  const bf16x8* wlds = reinterpret_cast<const bf16x8*>(smem);
  const int row0 = w * 32 + l15;

  for (int t = 0; t < Tn; ++t) {
    f32x4 acc[2][8];
#pragma unroll
    for (int mt = 0; mt < 2; ++mt)
#pragma unroll
      for (int ct = 0; ct < 8; ++ct) acc[mt][ct] = (f32x4){0.f, 0.f, 0.f, 0.f};

    if (roleA && s == 0) {
      // x-partial producer
      if (t >= 1) {
        int guard = 0;
        for (;;) {
          int ok = 1;
          if (tid == 0) ok = ((int)ldf(&fA0r[g]) >= t);
          if (++guard > BAILLIM) ok = 1;
          if (__syncthreads_and(ok)) break;
          __builtin_amdgcn_s_sleep(1);
        }
      }
      const unsigned short* xt = xall + (size_t)t * (Bn * En);
#pragma unroll 2
      for (int kt = 0; kt < 16; ++kt) {
        bf16x8 a0 = *reinterpret_cast<const bf16x8*>(xt + (size_t)row0 * En + kt * 32 + kq * 8);
        bf16x8 a1 = *reinterpret_cast<const bf16x8*>(xt + (size_t)(row0 + 16) * En + kt * 32 + kq * 8);
        MFB8(kt, a0, a1);
      }
      float* dst = pbufA + (size_t)(g * 5 + 0) * 16384 + (size_t)tid * 64;
#pragma unroll
      for (int mt = 0; mt < 2; ++mt)
#pragma unroll
        for (int ct = 0; ct < 8; ++ct) st_p(dst + (mt * 8 + ct) * 4, acc[mt][ct]);
      drain_then_sync();
      if (tid == 0) stf(flags + FPA + (size_t)(g * 8 + 0) * 16, (uint32_t)(t + 1));
    } else if (roleA && s != 1) {
      // Whh0 partial, slice (s-1)*512
      {
        int guard = 0;
        for (;;) {
          int ok = 1;
          if (tid < 16) ok = ((int)ldf(&fA0r[tid]) >= t);
          if (++guard > BAILLIM) ok = 1;
          if (__syncthreads_and(ok)) break;
          __builtin_amdgcn_s_sleep(1);
        }
      }
      const unsigned short* hp = h0ring + (size_t)((t + R0 - 1) % R0) * HSLOT + (s - 1) * 512;
      KLOOP512(hp, Hn);
      float* dst = pbufA + (size_t)(g * 5 + s) * 16384 + (size_t)tid * 64;
#pragma unroll
      for (int mt = 0; mt < 2; ++mt)
#pragma unroll
        for (int ct = 0; ct < 8; ++ct) st_p(dst + (mt * 8 + ct) * 4, acc[mt][ct]);
      drain_then_sync();
      if (tid == 0) stf(flags + FPA + (size_t)(g * 8 + s) * 16, (uint32_t)(t + 1));
    } else if (roleA) {
      // s==1: reducer-A (own slice k in [0,512))
      {
        int guard = 0;
        const bool ring = (t >= R0);
        for (;;) {
          int ok = 1;
          if (tid < 16) ok = ((int)ldf(&fA0r[tid]) >= t);
          else if (ring && tid >= 32 && tid < 48)
            ok = ((int)ldf(&fB0r[tid - 32]) >= t - R0 + 1);
          if (++guard > BAILLIM) ok = 1;
          if (__syncthreads_and(ok)) break;
          __builtin_amdgcn_s_sleep(1);
        }
      }
      const unsigned short* hp = h0ring + (size_t)((t + R0 - 1) % R0) * HSLOT;
      KLOOP512(hp, Hn);
      {
        int guard = 0;
        for (;;) {
          int ok = 1;
          if (tid < 4) {
            const int js[4] = {0, 2, 3, 4};
            ok = ((int)ldf(flags + FPA + (size_t)(g * 8 + js[tid]) * 16) >= t + 1);
          }
          if (++guard > BAILLIM) ok = 1;
          if (__syncthreads_and(ok)) break;
          __builtin_amdgcn_s_sleep(1);
        }
      }
      ADD_PARTIAL(pbufA + (size_t)(g * 5 + 0) * 16384);
      ADD_PARTIAL(pbufA + (size_t)(g * 5 + 2) * 16384);
      ADD_PARTIAL(pbufA + (size_t)(g * 5 + 3) * 16384);
      ADD_PARTIAL(pbufA + (size_t)(g * 5 + 4) * 16384);
      unsigned short* hdst = h0ring + (size_t)(t % R0) * HSLOT;
#pragma unroll
      for (int mt = 0; mt < 2; ++mt) {
#pragma unroll
        for (int ct = 0; ct < 8; ++ct) {
          const int col = colbase + ct * 16 + l15;
          const float bb = bias0[col];
#pragma unroll
          for (int r = 0; r < 4; ++r) {
            float v = tanhf(acc[mt][ct][r] + bb);
            int bo = f2b(v);
            int p2 = __shfl_down(bo, 1);
            uint32_t pair = (uint32_t)(unsigned short)bo | ((uint32_t)(unsigned short)p2 << 16);
            uint32_t hi = __shfl_down((int)pair, 2);
            if ((l15 & 3) == 0) {
              const int row = w * 32 + mt * 16 + kq * 4 + r;
              u64 qv = (u64)pair | ((u64)hi << 32);
              st64((u64*)(hdst + (size_t)row * Hn + col), qv);
            }
          }
        }
      }
      drain_then_sync();
      if (tid < NREP) stf(flags + (size_t)tid * 1024 + g, (uint32_t)(t + 1));
    } else if (s < 4) {
      // roleB Wih1 partial on h0[t]
      {
        int guard = 0;
        for (;;) {
          int ok = 1;
          if (tid < 16) ok = ((int)ldf(&fA0r[tid]) >= t + 1);
          else if (tid == 16) ok = ((int)ldf(&fB0r[g]) >= t);  // race-fix
          if (++guard > BAILLIM) ok = 1;
          if (__syncthreads_and(ok)) break;
          __builtin_amdgcn_s_sleep(1);
        }
      }
      const unsigned short* hp = h0ring + (size_t)(t % R0) * HSLOT + s * 512;
      KLOOP512(hp, Hn);
      float* dst = pbufB + (size_t)(g * 8 + s) * 16384 + (size_t)tid * 64;
#pragma unroll
      for (int mt = 0; mt < 2; ++mt)
#pragma unroll
        for (int ct = 0; ct < 8; ++ct) st_p(dst + (mt * 8 + ct) * 4, acc[mt][ct]);
      drain_then_sync();
      if (tid == 0) stf(flags + FPB + (size_t)(g * 8 + s) * 16, (uint32_t)(t + 1));
    } else if (s != 4) {
      // roleB Whh1 partial on h1[t-1], slice (s-4)*512
      {
        int guard = 0;
        for (;;) {
          int ok = 1;
          if (tid < 16) ok = ((int)ldf(&fB0r[tid]) >= t);
          if (++guard > BAILLIM) ok = 1;
          if (__syncthreads_and(ok)) break;
          __builtin_amdgcn_s_sleep(1);
        }
      }
      const unsigned short* hp = h1ring + (size_t)((t + R1 - 1) % R1) * HSLOT + (s - 4) * 512;
      KLOOP512(hp, Hn);
      float* dst = pbufB + (size_t)(g * 8 + s) * 16384 + (size_t)tid * 64;
#pragma unroll
      for (int mt = 0; mt < 2; ++mt)
#pragma unroll
        for (int ct = 0; ct < 8; ++ct) st_p(dst + (mt * 8 + ct) * 4, acc[mt][ct]);
      drain_then_sync();
      if (tid == 0) stf(flags + FPB + (size_t)(g * 8 + s) * 16, (uint32_t)(t + 1));
    } else {
      // s==4: reducer-B (own: Whh1 slice 0 on h1[t-1])
      {
        int guard = 0;
        for (;;) {
          int ok = 1;
          if (tid < 16) ok = ((int)ldf(&fB0r[tid]) >= t);
          if (++guard > BAILLIM) ok = 1;
          if (__syncthreads_and(ok)) break;
          __builtin_amdgcn_s_sleep(1);
        }
      }
      const unsigned short* hp = h1ring + (size_t)((t + R1 - 1) % R1) * HSLOT;
      KLOOP512(hp, Hn);
      {
        int guard = 0;
        for (;;) {
          int ok = 1;
          if (tid < 7) {
            const int js[7] = {0, 1, 2, 3, 5, 6, 7};
            ok = ((int)ldf(flags + FPB + (size_t)(g * 8 + js[tid]) * 16) >= t + 1);
          }
          if (++guard > BAILLIM) ok = 1;
          if (__syncthreads_and(ok)) break;
          __builtin_amdgcn_s_sleep(1);
        }
      }
      ADD_PARTIAL(pbufB + (size_t)(g * 8 + 0) * 16384);
      ADD_PARTIAL(pbufB + (size_t)(g * 8 + 1) * 16384);
      ADD_PARTIAL(pbufB + (size_t)(g * 8 + 2) * 16384);
      ADD_PARTIAL(pbufB + (size_t)(g * 8 + 3) * 16384);
      ADD_PARTIAL(pbufB + (size_t)(g * 8 + 5) * 16384);
      ADD_PARTIAL(pbufB + (size_t)(g * 8 + 6) * 16384);
      ADD_PARTIAL(pbufB + (size_t)(g * 8 + 7) * 16384);
      unsigned short* hdst = h1ring + (size_t)(t % R1) * HSLOT;
#pragma unroll
      for (int mt = 0; mt < 2; ++mt) {
#pragma unroll
        for (int ct = 0; ct < 8; ++ct) {
          const int col = colbase + ct * 16 + l15;
          const float bb = bias1[col];
#pragma unroll
          for (int r = 0; r < 4; ++r) {
            float v = tanhf(acc[mt][ct][r] + bb);
            int bo = f2b(v);
            int p2 = __shfl_down(bo, 1);
            uint32_t pair = (uint32_t)(unsigned short)bo | ((uint32_t)(unsigned short)p2 << 16);
            uint32_t hi = __shfl_down((int)pair, 2);
            if ((l15 & 3) == 0) {
              const int row = w * 32 + mt * 16 + kq * 4 + r;
              u64 qv = (u64)pair | ((u64)hi << 32);
              st64((u64*)(hdst + (size_t)row * Hn + col), qv);
            }
          }
        }
      }
      drain_then_sync();
      if (tid < NREP) stf(flags + (size_t)tid * 1024 + 64 + g, (uint32_t)(t + 1));
    }
  }
}

// ---------------- head (proven) ----------------
__global__ __launch_bounds__(256) void head1(const uint4* __restrict__ imgW1,
                                             const unsigned short* __restrict__ h1f,
                                             const float* __restrict__ b1,
                                             unsigned short* __restrict__ a1) {
  __shared__ uint4 smem[4096];
  const int tid = threadIdx.x;
  const int w = tid >> 6, l = tid & 63, l15 = l & 15, kq = l >> 4;
  const int g = blockIdx.x;
  const uint4* src = imgW1 + (size_t)g * 4096;
  for (int i = tid; i < 4096; i += 256) smem[i] = src[i];
  __syncthreads();
  const bf16x8* wlds = reinterpret_cast<const bf16x8*>(smem);
  const int row0 = w * 32 + l15;
  f32x4 acc[2];
  acc[0] = (f32x4){0.f, 0.f, 0.f, 0.f};
  acc[1] = (f32x4){0.f, 0.f, 0.f, 0.f};
#pragma unroll 4
  for (int kt = 0; kt < 64; ++kt) {
    bf16x8 af0 = *reinterpret_cast<const bf16x8*>(h1f + (size_t)row0 * Hn + kt * 32 + kq * 8);
    bf16x8 af1 = *reinterpret_cast<const bf16x8*>(h1f + (size_t)(row0 + 16) * Hn + kt * 32 + kq * 8);
    bf16x8 bf = wlds[kt * 64 + l];
    acc[0] = __builtin_amdgcn_mfma_f32_16x16x32_bf16(af0, bf, acc[0], 0, 0, 0);
    acc[1] = __builtin_amdgcn_mfma_f32_16x16x32_bf16(af1, bf, acc[1], 0, 0, 0);
  }
  const int col = g * 16 + l15;
  const float bb = b1[col];
#pragma unroll
  for (int mt = 0; mt < 2; ++mt)
#pragma unroll
    for (int r = 0; r < 4; ++r) {
      float v = fmaxf(acc[mt][r] + bb, 0.f);
      const int row = w * 32 + mt * 16 + kq * 4 + r;
      a1[(size_t)row * En + col] = f2b(v);
    }
}

__global__ __launch_bounds__(256) void head2(const uint4* __restrict__ imgW2,
                                             const unsigned short* __restrict__ a1,
                                             const float* __restrict__ b2,
                                             float* __restrict__ out) {
  __shared__ uint4 smem[4096];
  const int tid = threadIdx.x;
  const int w = tid >> 6, l = tid & 63, l15 = l & 15, kq = l >> 4;
  const int g = blockIdx.x;
  const uint4* src = imgW2 + (size_t)g * 4096;
  for (int i = tid; i < 4096; i += 256) smem[i] = src[i];
  __syncthreads();
  const bf16x8* wlds = reinterpret_cast<const bf16x8*>(smem);
  const int row0 = w * 32 + l15;
  f32x4 acc[2][4];
#pragma unroll
  for (int mt = 0; mt < 2; ++mt)
#pragma unroll
    for (int ct = 0; ct < 4; ++ct) acc[mt][ct] = (f32x4){0.f, 0.f, 0.f, 0.f};
#pragma unroll
  for (int kt = 0; kt < 16; ++kt) {
    bf16x8 af0 = *reinterpret_cast<const bf16x8*>(a1 + (size_t)row0 * En + kt * 32 + kq * 8);
    bf16x8 af1 = *reinterpret_cast<const bf16x8*>(a1 + (size_t)(row0 + 16) * En + kt * 32 + kq * 8);
#pragma unroll
    for (int ct = 0; ct < 4; ++ct) {
      bf16x8 bf = wlds[(kt * 4 + ct) * 64 + l];
      acc[0][ct] = __builtin_amdgcn_mfma_f32_16x16x32_bf16(af0, bf, acc[0][ct], 0, 0, 0);
      acc[1][ct] = __builtin_amdgcn_mfma_f32_16x16x32_bf16(af1, bf, acc[1][ct], 0, 0, 0);
    }
  }
#pragma unroll
  for (int mt = 0; mt < 2; ++mt)
#pragma unroll
    for (int ct = 0; ct < 4; ++ct) {
      const int col = g * 64 + ct * 16 + l15;
      const float bb = b2[col];
#pragma unroll
      for (int r = 0; r < 4; ++r) {
        const int row = w * 32 + mt * 16 + kq * 4 + r;
        out[(size_t)row * Vn + col] = acc[mt][ct][r] + bb;
      }
    }
}

// ---------------- launch ----------------
extern "C" void kernel_launch(void* const* d_in, const int* in_sizes, int n_in,
                              void* d_out, int out_size, void* d_ws, size_t ws_size,
                              hipStream_t stream) {
  (void)in_sizes; (void)n_in; (void)out_size;
  const int* ids    = (const int*)d_in[0];
  const float* emb  = (const float*)d_in[1];
  const float* Wih0 = (const float*)d_in[2];
  const float* Whh0 = (const float*)d_in[3];
  const float* bih0 = (const float*)d_in[4];
  const float* bhh0 = (const float*)d_in[5];
  const float* Wih1 = (const float*)d_in[6];
  const float* Whh1 = (const float*)d_in[7];
  const float* bih1 = (const float*)d_in[8];
  const float* bhh1 = (const float*)d_in[9];
  const float* W1   = (const float*)d_in[10];
  const float* b1   = (const float*)d_in[11];
  const float* W2   = (const float*)d_in[12];
  const float* b2   = (const float*)d_in[13];
  float* out = (float*)d_out;

  char* ws = (char*)d_ws;
  size_t o = 0;
  auto alloc = [&](size_t bytes) -> char* {
    char* p = ws + o;
    o += (bytes + 255) & ~(size_t)255;
    return p;
  };
  uint32_t* flags = (uint32_t*)alloc(FLAG_WORDS * 4);
  float* bias0 = (float*)alloc(Hn * 4);
  float* bias1 = (float*)alloc(Hn * 4);
  unsigned short* h0ring = (unsigned short*)alloc((size_t)R0 * HSLOT * 2);
  unsigned short* h1ring = (unsigned short*)alloc((size_t)R1 * HSLOT * 2);
  float* pbufA = (float*)alloc(16ull * 5 * 16384 * 4);
  float* pbufB = (float*)alloc(16ull * 8 * 16384 * 4);
  unsigned short* a1 = (unsigned short*)alloc((size_t)Bn * En * 2);
  uint4* imgWih0 = (uint4*)alloc(16ull * 8192 * 16);
  uint4* imgWhh0 = (uint4*)alloc(64ull * 8192 * 16);
  uint4* imgWih1 = (uint4*)alloc(64ull * 8192 * 16);
  uint4* imgWhh1 = (uint4*)alloc(64ull * 8192 * 16);
  uint4* imgW1 = (uint4*)alloc(32ull * 4096 * 16);
  uint4* imgW2 = (uint4*)alloc(500ull * 4096 * 16);
  uint4* xall  = (uint4*)alloc((size_t)Tn * Bn * En * 2);
  if (o > ws_size) return;  // fail visibly, no OOB

  zero3<<<512, 256, 0, stream>>>(flags, FLAG_WORDS,
                                 (uint32_t*)(h0ring + (size_t)(R0 - 1) * HSLOT), 131072,
                                 (uint32_t*)(h1ring + (size_t)(R1 - 1) * HSLOT), 131072);
  pack_bias<<<8, 256, 0, stream>>>(bih0, bhh0, bih1, bhh1, bias0, bias1);
  pack_seg<<<512, 256, 0, stream>>>(Wih0, 512, 1, imgWih0);
  pack_seg<<<2048, 256, 0, stream>>>(Whh0, 2048, 4, imgWhh0);
  pack_seg<<<2048, 256, 0, stream>>>(Wih1, 2048, 4, imgWih1);
  pack_seg<<<2048, 256, 0, stream>>>(Whh1, 2048, 4, imgWhh1);
  pack_imgW1<<<512, 256, 0, stream>>>(W1, imgW1);
  pack_imgW2<<<8000, 256, 0, stream>>>(W2, imgW2);
  gather_x<<<16384, 256, 0, stream>>>(ids, emb, xall);

  rnn_persist<<<208, 256, 0, stream>>>(imgWih0, imgWhh0, imgWih1, imgWhh1,
                                       (const unsigned short*)xall, h0ring, h1ring,
                                       pbufA, pbufB, bias0, bias1, flags);

  head1<<<32, 256, 0, stream>>>(imgW1, h1ring + (size_t)(511 % R1) * HSLOT, b1, a1);
  head2<<<500, 256, 0, stream>>>(imgW2, a1, b2, out);
}

// Round 12
// 27967.361 us; speedup vs baseline: 1.2859x; 1.2859x over previous
//
#include <hip/hip_runtime.h>
#include <hip/hip_bf16.h>
#include <stdint.h>

// Problem dims
#define Bn 128
#define Tn 512
#define En 512
#define Hn 2048
#define Vn 32000
#define R0 8
#define R1 4
#define HSLOT (Bn*Hn)

// flags: reps r*1024 (+0 fA0[16], +64 fB0[16]); FPA/FPB private lines
#define NREP 8
#define FPA 8192       // + (g*8+s)*16
#define FPB 10240      // + (g*8+s)*16
#define FLAG_WORDS 16384
#define BAILLIM 16384

typedef float f32x4 __attribute__((ext_vector_type(4)));
typedef short bf16x8 __attribute__((ext_vector_type(8)));
typedef unsigned long long u64;

__device__ __forceinline__ unsigned short f2b(float f) {
  uint32_t x = __builtin_bit_cast(uint32_t, f);
  uint32_t r = x + 0x7FFFu + ((x >> 16) & 1u);
  return (unsigned short)(r >> 16);
}

// MALL ops (r2-r9 proven)
__device__ __forceinline__ uint32_t ldf(const uint32_t* p) {
  return __hip_atomic_load(p, __ATOMIC_RELAXED, __HIP_MEMORY_SCOPE_AGENT);
}
__device__ __forceinline__ void stf(uint32_t* p, uint32_t v) {
  __hip_atomic_store(p, v, __ATOMIC_RELAXED, __HIP_MEMORY_SCOPE_AGENT);
}
__device__ __forceinline__ void st64(u64* p, u64 v) {
  __hip_atomic_store(p, v, __ATOMIC_RELAXED, __HIP_MEMORY_SCOPE_AGENT);
}
union F32x4u { f32x4 v; u64 q[2]; };
__device__ __forceinline__ void st_p(float* p, f32x4 x) {
  F32x4u u; u.v = x;
  st64((u64*)p, u.q[0]); st64((u64*)p + 1, u.q[1]);
}
__device__ __forceinline__ void drain_then_sync() {
  asm volatile("s_waitcnt vmcnt(0)" ::: "memory");
  __syncthreads();
}

// 16-deep MALL-coherent loads (sc0 sc1 — r7-proven) for h reads: 8 kt-tiles x 2 rows
#define LD16_MALL(PA, PB) \
  asm volatile( \
      "global_load_dwordx4 %[t0], %[a], off sc0 sc1\n\t" \
      "global_load_dwordx4 %[t1], %[a], off offset:64 sc0 sc1\n\t" \
      "global_load_dwordx4 %[t2], %[a], off offset:128 sc0 sc1\n\t" \
      "global_load_dwordx4 %[t3], %[a], off offset:192 sc0 sc1\n\t" \
      "global_load_dwordx4 %[t4], %[a], off offset:256 sc0 sc1\n\t" \
      "global_load_dwordx4 %[t5], %[a], off offset:320 sc0 sc1\n\t" \
      "global_load_dwordx4 %[t6], %[a], off offset:384 sc0 sc1\n\t" \
      "global_load_dwordx4 %[t7], %[a], off offset:448 sc0 sc1\n\t" \
      "global_load_dwordx4 %[t8], %[b], off sc0 sc1\n\t" \
      "global_load_dwordx4 %[t9], %[b], off offset:64 sc0 sc1\n\t" \
      "global_load_dwordx4 %[ta], %[b], off offset:128 sc0 sc1\n\t" \
      "global_load_dwordx4 %[tb], %[b], off offset:192 sc0 sc1\n\t" \
      "global_load_dwordx4 %[tc], %[b], off offset:256 sc0 sc1\n\t" \
      "global_load_dwordx4 %[td], %[b], off offset:320 sc0 sc1\n\t" \
      "global_load_dwordx4 %[te], %[b], off offset:384 sc0 sc1\n\t" \
      "global_load_dwordx4 %[tf], %[b], off offset:448 sc0 sc1\n\t" \
      "s_waitcnt vmcnt(0)" \
      : [t0]"=&v"(v0), [t1]"=&v"(v1), [t2]"=&v"(v2), [t3]"=&v"(v3), \
        [t4]"=&v"(v4), [t5]"=&v"(v5), [t6]"=&v"(v6), [t7]"=&v"(v7), \
        [t8]"=&v"(v8), [t9]"=&v"(v9), [ta]"=&v"(va), [tb]"=&v"(vb), \
        [tc]"=&v"(vc), [td]"=&v"(vd), [te]"=&v"(ve), [tf]"=&v"(vf) \
      : [a]"v"(PA), [b]"v"(PB) : "memory"); \
  __builtin_amdgcn_sched_barrier(0)

// 16-chunk partial fetch, WAVE-INTERLEAVED layout (v13 bug-class fix):
// chunk c at slot + w*4096 + c*256 + l*4 floats -> every instruction covers a
// contiguous 1KiB (64 lanes x 16B). 4 base regs, chunk strides 1KiB, one drain.
#define LD16P(B0, B1, B2, B3) \
  asm volatile( \
      "global_load_dwordx4 %[t0], %[a], off sc0 sc1\n\t" \
      "global_load_dwordx4 %[t1], %[a], off offset:1024 sc0 sc1\n\t" \
      "global_load_dwordx4 %[t2], %[a], off offset:2048 sc0 sc1\n\t" \
      "global_load_dwordx4 %[t3], %[a], off offset:3072 sc0 sc1\n\t" \
      "global_load_dwordx4 %[t4], %[b], off sc0 sc1\n\t" \
      "global_load_dwordx4 %[t5], %[b], off offset:1024 sc0 sc1\n\t" \
      "global_load_dwordx4 %[t6], %[b], off offset:2048 sc0 sc1\n\t" \
      "global_load_dwordx4 %[t7], %[b], off offset:3072 sc0 sc1\n\t" \
      "global_load_dwordx4 %[t8], %[c], off sc0 sc1\n\t" \
      "global_load_dwordx4 %[t9], %[c], off offset:1024 sc0 sc1\n\t" \
      "global_load_dwordx4 %[ta], %[c], off offset:2048 sc0 sc1\n\t" \
      "global_load_dwordx4 %[tb], %[c], off offset:3072 sc0 sc1\n\t" \
      "global_load_dwordx4 %[tc], %[d], off sc0 sc1\n\t" \
      "global_load_dwordx4 %[td], %[d], off offset:1024 sc0 sc1\n\t" \
      "global_load_dwordx4 %[te], %[d], off offset:2048 sc0 sc1\n\t" \
      "global_load_dwordx4 %[tf], %[d], off offset:3072 sc0 sc1\n\t" \
      "s_waitcnt vmcnt(0)" \
      : [t0]"=&v"(q0), [t1]"=&v"(q1), [t2]"=&v"(q2), [t3]"=&v"(q3), \
        [t4]"=&v"(q4), [t5]"=&v"(q5), [t6]"=&v"(q6), [t7]"=&v"(q7), \
        [t8]"=&v"(q8), [t9]"=&v"(q9), [ta]"=&v"(qa), [tb]"=&v"(qb), \
        [tc]"=&v"(qc), [td]"=&v"(qd), [te]"=&v"(qe), [tf]"=&v"(qf) \
      : [a]"v"(B0), [b]"v"(B1), [c]"v"(B2), [d]"v"(B3) : "memory"); \
  __builtin_amdgcn_sched_barrier(0)

// ---------------- init / pack kernels ----------------

__global__ void zero3(uint32_t* a, int na, uint32_t* b, int nb, uint32_t* c, int nc) {
  int i = blockIdx.x * 256 + threadIdx.x;
  if (i < na) a[i] = 0u;
  if (i < nb) b[i] = 0u;
  if (i < nc) c[i] = 0u;
}

__global__ void pack_bias(const float* bih0, const float* bhh0,
                          const float* bih1, const float* bhh1,
                          float* bias0, float* bias1) {
  int i = blockIdx.x * 256 + threadIdx.x;
  bias0[i] = bih0[i] + bhh0[i];
  bias1[i] = bih1[i] + bhh1[i];
}

// 16 groups x 128 cols, nseg K-segments of 512. packet p=(kt*8+ct)*64+l within
// (g,seg) slice of 8192 packets. lane l elem j: src[col=g*128+ct*16+(l&15)]
// [k = seg*512 + kt*32 + (l>>4)*8 + j], src row-major [2048 x Ksrc].
__global__ void pack_seg(const float* __restrict__ src, int Ksrc, int nseg,
                         uint4* __restrict__ img) {
  int tid = blockIdx.x * 256 + threadIdx.x;
  int per = nseg * 8192;
  int g = tid / per, r1 = tid - g * per;
  int seg = r1 >> 13, p = r1 & 8191;
  int kt = p >> 9, ct = (p >> 6) & 7, l = p & 63;
  int col = g * 128 + ct * 16 + (l & 15);
  int k = seg * 512 + kt * 32 + (l >> 4) * 8;
  const float* s = src + (size_t)col * Ksrc + k;
  unsigned short o[8];
#pragma unroll
  for (int j = 0; j < 8; ++j) o[j] = f2b(s[j]);
  img[tid] = *reinterpret_cast<uint4*>(o);
}

__global__ void pack_imgW1(const float* __restrict__ W1, uint4* __restrict__ img) {
  int tid = blockIdx.x * 256 + threadIdx.x;
  int grp = tid >> 12;
  int p = tid & 4095;
  int l = p & 63;
  int kt = p >> 6;
  int col = grp * 16 + (l & 15);
  int k0 = kt * 32 + (l >> 4) * 8;
  const float* src = W1 + (size_t)col * Hn + k0;
  unsigned short o[8];
#pragma unroll
  for (int j = 0; j < 8; ++j) o[j] = f2b(src[j]);
  img[tid] = *reinterpret_cast<uint4*>(o);
}

__global__ void pack_imgW2(const float* __restrict__ W2, uint4* __restrict__ img) {
  int tid = blockIdx.x * 256 + threadIdx.x;
  int grp = tid >> 12;
  int p = tid & 4095;
  int l = p & 63;
  int ckt = p >> 6;
  int ct = ckt & 3, kt = ckt >> 2;
  int col = grp * 64 + ct * 16 + (l & 15);
  int k0 = kt * 32 + (l >> 4) * 8;
  const float* src = W2 + (size_t)col * En + k0;
  unsigned short o[8];
#pragma unroll
  for (int j = 0; j < 8; ++j) o[j] = f2b(src[j]);
  img[tid] = *reinterpret_cast<uint4*>(o);
}

__global__ void gather_x(const int* __restrict__ ids, const float* __restrict__ emb,
                         uint4* __restrict__ xall) {
  int tid = blockIdx.x * 256 + threadIdx.x;
  int t = tid >> 13;
  int r = tid & 8191;
  int b = r >> 6;
  int e8 = r & 63;
  int id = ids[b * Tn + t];
  const float* src = emb + (size_t)id * En + e8 * 8;
  unsigned short o[8];
#pragma unroll
  for (int j = 0; j < 8; ++j) o[j] = f2b(src[j]);
  xall[tid] = *reinterpret_cast<uint4*>(o);
}

// ---------------- persistent RNN v14: v13 + wave-interleaved pbuf layout ----------
// 208 blocks x 256 thr, 1/CU. Roles by blockIdx (no XCD logic):
//  blk<80:  roleA, g=blk/5, s=blk%5. s0: Wih0.x_t. s1..4: Whh0 K-slice (s-1)*512
//           of h0[t-1]. s1 = reducer: + partials + bias0 -> tanh -> h0ring, fA0.
//  blk>=80: roleB, bb=blk-80, g=bb>>3, s=bb&7. s0..3: Wih1 slice s*512 of h0[t].
//           s4..7: Whh1 slice (s-4)*512 of h1[t-1]. s4 = reducer -> h1ring, fB0.
// Partial slot layout (v13 perf-bug fix): chunk c=mt*8+ct of thread (w,l) at
// slot*16384 + w*4096 + c*256 + l*4 floats -> all 64 lanes of any one store/load
// instruction cover one contiguous 1KiB run (v13's tid*64 scattered lanes 256B
// apart -> 4x HBM write amplification, 24GB WRITE_SIZE, 36ms).

#define MFB8(KT, A0, A1) do { \
    bf16x8 bw_; \
    _Pragma("unroll") \
    for (int ct_ = 0; ct_ < 8; ++ct_) { \
      bw_ = wlds[((KT) * 8 + ct_) * 64 + l]; \
      acc[0][ct_] = __builtin_amdgcn_mfma_f32_16x16x32_bf16(A0, bw_, acc[0][ct_], 0, 0, 0); \
      acc[1][ct_] = __builtin_amdgcn_mfma_f32_16x16x32_bf16(A1, bw_, acc[1][ct_], 0, 0, 0); \
    } \
  } while (0)

// K=512 slice from BASE (row-major, stride STRIDE elements), MALL-coherent
#define KLOOP512(BASE, STRIDE) do { \
    const unsigned short* pr0_ = (BASE) + (size_t)row0 * (STRIDE) + kq * 8; \
    const unsigned short* pr1_ = pr0_ + (size_t)16 * (STRIDE); \
    _Pragma("unroll") \
    for (int b_ = 0; b_ < 2; ++b_) { \
      const unsigned short* pa_ = pr0_ + b_ * 256; \
      const unsigned short* pb_ = pr1_ + b_ * 256; \
      bf16x8 v0,v1,v2,v3,v4,v5,v6,v7,v8,v9,va,vb,vc,vd,ve,vf; \
      LD16_MALL(pa_, pb_); \
      const int kb_ = b_ * 8; \
      MFB8(kb_+0, v0, v8); MFB8(kb_+1, v1, v9); MFB8(kb_+2, v2, va); MFB8(kb_+3, v3, vb); \
      MFB8(kb_+4, v4, vc); MFB8(kb_+5, v5, vd); MFB8(kb_+6, v6, ve); MFB8(kb_+7, v7, vf); \
    } \
  } while (0)

// store partials: chunk c at slot + w*4096 + c*256 + l*4 (floats)
#define ST_PARTIAL(DST) do { \
    float* d_ = (DST) + (size_t)w * 4096 + (size_t)l * 4; \
    _Pragma("unroll") \
    for (int mt_ = 0; mt_ < 2; ++mt_) \
      _Pragma("unroll") \
      for (int ct_ = 0; ct_ < 8; ++ct_) \
        st_p(d_ + (mt_ * 8 + ct_) * 256, acc[mt_][ct_]); \
  } while (0)

#define ADD_PARTIAL(SRC) do { \
    f32x4 q0,q1,q2,q3,q4,q5,q6,q7,q8,q9,qa,qb,qc,qd,qe,qf; \
    const float* b0_ = (SRC) + (size_t)w * 4096 + (size_t)l * 4; \
    const float* b1_ = b0_ + 1024; \
    const float* b2_ = b0_ + 2048; \
    const float* b3_ = b0_ + 3072; \
    LD16P(b0_, b1_, b2_, b3_); \
    acc[0][0]+=q0; acc[0][1]+=q1; acc[0][2]+=q2; acc[0][3]+=q3; \
    acc[0][4]+=q4; acc[0][5]+=q5; acc[0][6]+=q6; acc[0][7]+=q7; \
    acc[1][0]+=q8; acc[1][1]+=q9; acc[1][2]+=qa; acc[1][3]+=qb; \
    acc[1][4]+=qc; acc[1][5]+=qd; acc[1][6]+=qe; acc[1][7]+=qf; \
  } while (0)

__global__ __launch_bounds__(256, 1) void rnn_persist(
    const uint4* __restrict__ imgWih0, const uint4* __restrict__ imgWhh0,
    const uint4* __restrict__ imgWih1, const uint4* __restrict__ imgWhh1,
    const unsigned short* __restrict__ xall,
    unsigned short* __restrict__ h0ring, unsigned short* __restrict__ h1ring,
    float* __restrict__ pbufA, float* __restrict__ pbufB,
    const float* __restrict__ bias0, const float* __restrict__ bias1,
    uint32_t* flags) {
  __shared__ uint4 smem[8192];  // 128 KiB -> 1 block/CU, 208 blocks all resident
  const int tid = threadIdx.x;
  const int w = tid >> 6, l = tid & 63, l15 = l & 15, kq = l >> 4;
  const int blk = blockIdx.x;
  const bool roleA = (blk < 80);
  const int g = roleA ? (blk / 5) : ((blk - 80) >> 3);
  const int s = roleA ? (blk % 5) : ((blk - 80) & 7);
  const int myrep = blk & (NREP - 1);
  const uint32_t* fA0r = flags + (size_t)myrep * 1024;
  const uint32_t* fB0r = flags + (size_t)myrep * 1024 + 64;
  const int colbase = g * 128;

  {  // stage weights (128 KiB slice)
    const uint4* wsrc;
    if (roleA) wsrc = (s == 0) ? (imgWih0 + (size_t)g * 8192)
                               : (imgWhh0 + (size_t)(g * 4 + s - 1) * 8192);
    else       wsrc = (s < 4)  ? (imgWih1 + (size_t)(g * 4 + s) * 8192)
                               : (imgWhh1 + (size_t)(g * 4 + s - 4) * 8192);
    for (int i = tid; i < 8192; i += 256) smem[i] = wsrc[i];
  }
  __syncthreads();
  const bf16x8* wlds = reinterpret_cast<const bf16x8*>(smem);
  const int row0 = w * 32 + l15;

  for (int t = 0; t < Tn; ++t) {
    f32x4 acc[2][8];
#pragma unroll
    for (int mt = 0; mt < 2; ++mt)
#pragma unroll
      for (int ct = 0; ct < 8; ++ct) acc[mt][ct] = (f32x4){0.f, 0.f, 0.f, 0.f};

    if (roleA && s == 0) {
      // x-partial producer
      if (t >= 1) {
        int guard = 0;
        for (;;) {
          int ok = 1;
          if (tid == 0) ok = ((int)ldf(&fA0r[g]) >= t);
          if (++guard > BAILLIM) ok = 1;
          if (__syncthreads_and(ok)) break;
          __builtin_amdgcn_s_sleep(1);
        }
      }
      const unsigned short* xt = xall + (size_t)t * (Bn * En);
#pragma unroll 2
      for (int kt = 0; kt < 16; ++kt) {
        bf16x8 a0 = *reinterpret_cast<const bf16x8*>(xt + (size_t)row0 * En + kt * 32 + kq * 8);
        bf16x8 a1 = *reinterpret_cast<const bf16x8*>(xt + (size_t)(row0 + 16) * En + kt * 32 + kq * 8);
        MFB8(kt, a0, a1);
      }
      ST_PARTIAL(pbufA + (size_t)(g * 5 + 0) * 16384);
      drain_then_sync();
      if (tid == 0) stf(flags + FPA + (size_t)(g * 8 + 0) * 16, (uint32_t)(t + 1));
    } else if (roleA && s != 1) {
      // Whh0 partial, slice (s-1)*512
      {
        int guard = 0;
        for (;;) {
          int ok = 1;
          if (tid < 16) ok = ((int)ldf(&fA0r[tid]) >= t);
          if (++guard > BAILLIM) ok = 1;
          if (__syncthreads_and(ok)) break;
          __builtin_amdgcn_s_sleep(1);
        }
      }
      const unsigned short* hp = h0ring + (size_t)((t + R0 - 1) % R0) * HSLOT + (s - 1) * 512;
      KLOOP512(hp, Hn);
      ST_PARTIAL(pbufA + (size_t)(g * 5 + s) * 16384);
      drain_then_sync();
      if (tid == 0) stf(flags + FPA + (size_t)(g * 8 + s) * 16, (uint32_t)(t + 1));
    } else if (roleA) {
      // s==1: reducer-A (own slice k in [0,512))
      {
        int guard = 0;
        const bool ring = (t >= R0);
        for (;;) {
          int ok = 1;
          if (tid < 16) ok = ((int)ldf(&fA0r[tid]) >= t);
          else if (ring && tid >= 32 && tid < 48)
            ok = ((int)ldf(&fB0r[tid - 32]) >= t - R0 + 1);
          if (++guard > BAILLIM) ok = 1;
          if (__syncthreads_and(ok)) break;
          __builtin_amdgcn_s_sleep(1);
        }
      }
      const unsigned short* hp = h0ring + (size_t)((t + R0 - 1) % R0) * HSLOT;
      KLOOP512(hp, Hn);
      {
        int guard = 0;
        for (;;) {
          int ok = 1;
          if (tid < 4) {
            const int js[4] = {0, 2, 3, 4};
            ok = ((int)ldf(flags + FPA + (size_t)(g * 8 + js[tid]) * 16) >= t + 1);
          }
          if (++guard > BAILLIM) ok = 1;
          if (__syncthreads_and(ok)) break;
          __builtin_amdgcn_s_sleep(1);
        }
      }
      ADD_PARTIAL(pbufA + (size_t)(g * 5 + 0) * 16384);
      ADD_PARTIAL(pbufA + (size_t)(g * 5 + 2) * 16384);
      ADD_PARTIAL(pbufA + (size_t)(g * 5 + 3) * 16384);
      ADD_PARTIAL(pbufA + (size_t)(g * 5 + 4) * 16384);
      unsigned short* hdst = h0ring + (size_t)(t % R0) * HSLOT;
#pragma unroll
      for (int mt = 0; mt < 2; ++mt) {
#pragma unroll
        for (int ct = 0; ct < 8; ++ct) {
          const int col = colbase + ct * 16 + l15;
          const float bb = bias0[col];
#pragma unroll
          for (int r = 0; r < 4; ++r) {
            float v = tanhf(acc[mt][ct][r] + bb);
            int bo = f2b(v);
            int p2 = __shfl_down(bo, 1);
            uint32_t pair = (uint32_t)(unsigned short)bo | ((uint32_t)(unsigned short)p2 << 16);
            uint32_t hi = __shfl_down((int)pair, 2);
            if ((l15 & 3) == 0) {
              const int row = w * 32 + mt * 16 + kq * 4 + r;
              u64 qv = (u64)pair | ((u64)hi << 32);
              st64((u64*)(hdst + (size_t)row * Hn + col), qv);
            }
          }
        }
      }
      drain_then_sync();
      if (tid < NREP) stf(flags + (size_t)tid * 1024 + g, (uint32_t)(t + 1));
    } else if (s < 4) {
      // roleB Wih1 partial on h0[t]
      {
        int guard = 0;
        for (;;) {
          int ok = 1;
          if (tid < 16) ok = ((int)ldf(&fA0r[tid]) >= t + 1);
          else if (tid == 16) ok = ((int)ldf(&fB0r[g]) >= t);  // race-fix
          if (++guard > BAILLIM) ok = 1;
          if (__syncthreads_and(ok)) break;
          __builtin_amdgcn_s_sleep(1);
        }
      }
      const unsigned short* hp = h0ring + (size_t)(t % R0) * HSLOT + s * 512;
      KLOOP512(hp, Hn);
      ST_PARTIAL(pbufB + (size_t)(g * 8 + s) * 16384);
      drain_then_sync();
      if (tid == 0) stf(flags + FPB + (size_t)(g * 8 + s) * 16, (uint32_t)(t + 1));
    } else if (s != 4) {
      // roleB Whh1 partial on h1[t-1], slice (s-4)*512
      {
        int guard = 0;
        for (;;) {
          int ok = 1;
          if (tid < 16) ok = ((int)ldf(&fB0r[tid]) >= t);
          if (++guard > BAILLIM) ok = 1;
          if (__syncthreads_and(ok)) break;
          __builtin_amdgcn_s_sleep(1);
        }
      }
      const unsigned short* hp = h1ring + (size_t)((t + R1 - 1) % R1) * HSLOT + (s - 4) * 512;
      KLOOP512(hp, Hn);
      ST_PARTIAL(pbufB + (size_t)(g * 8 + s) * 16384);
      drain_then_sync();
      if (tid == 0) stf(flags + FPB + (size_t)(g * 8 + s) * 16, (uint32_t)(t + 1));
    } else {
      // s==4: reducer-B (own: Whh1 slice 0 on h1[t-1])
      {
        int guard = 0;
        for (;;) {
          int ok = 1;
          if (tid < 16) ok = ((int)ldf(&fB0r[tid]) >= t);
          if (++guard > BAILLIM) ok = 1;
          if (__syncthreads_and(ok)) break;
          __builtin_amdgcn_s_sleep(1);
        }
      }
      const unsigned short* hp = h1ring + (size_t)((t + R1 - 1) % R1) * HSLOT;
      KLOOP512(hp, Hn);
      {
        int guard = 0;
        for (;;) {
          int ok = 1;
          if (tid < 7) {
            const int js[7] = {0, 1, 2, 3, 5, 6, 7};
            ok = ((int)ldf(flags + FPB + (size_t)(g * 8 + js[tid]) * 16) >= t + 1);
          }
          if (++guard > BAILLIM) ok = 1;
          if (__syncthreads_and(ok)) break;
          __builtin_amdgcn_s_sleep(1);
        }
      }
      ADD_PARTIAL(pbufB + (size_t)(g * 8 + 0) * 16384);
      ADD_PARTIAL(pbufB + (size_t)(g * 8 + 1) * 16384);
      ADD_PARTIAL(pbufB + (size_t)(g * 8 + 2) * 16384);
      ADD_PARTIAL(pbufB + (size_t)(g * 8 + 3) * 16384);
      ADD_PARTIAL(pbufB + (size_t)(g * 8 + 5) * 16384);
      ADD_PARTIAL(pbufB + (size_t)(g * 8 + 6) * 16384);
      ADD_PARTIAL(pbufB + (size_t)(g * 8 + 7) * 16384);
      unsigned short* hdst = h1ring + (size_t)(t % R1) * HSLOT;
#pragma unroll
      for (int mt = 0; mt < 2; ++mt) {
#pragma unroll
        for (int ct = 0; ct < 8; ++ct) {
          const int col = colbase + ct * 16 + l15;
          const float bb = bias1[col];
#pragma unroll
          for (int r = 0; r < 4; ++r) {
            float v = tanhf(acc[mt][ct][r] + bb);
            int bo = f2b(v);
            int p2 = __shfl_down(bo, 1);
            uint32_t pair = (uint32_t)(unsigned short)bo | ((uint32_t)(unsigned short)p2 << 16);
            uint32_t hi = __shfl_down((int)pair, 2);
            if ((l15 & 3) == 0) {
              const int row = w * 32 + mt * 16 + kq * 4 + r;
              u64 qv = (u64)pair | ((u64)hi << 32);
              st64((u64*)(hdst + (size_t)row * Hn + col), qv);
            }
          }
        }
      }
      drain_then_sync();
      if (tid < NREP) stf(flags + (size_t)tid * 1024 + 64 + g, (uint32_t)(t + 1));
    }
  }
}

// ---------------- head (proven) ----------------
__global__ __launch_bounds__(256) void head1(const uint4* __restrict__ imgW1,
                                             const unsigned short* __restrict__ h1f,
                                             const float* __restrict__ b1,
                                             unsigned short* __restrict__ a1) {
  __shared__ uint4 smem[4096];
  const int tid = threadIdx.x;
  const int w = tid >> 6, l = tid & 63, l15 = l & 15, kq = l >> 4;
  const int g = blockIdx.x;
  const uint4* src = imgW1 + (size_t)g * 4096;
  for (int i = tid; i < 4096; i += 256) smem[i] = src[i];
  __syncthreads();
  const bf16x8* wlds = reinterpret_cast<const bf16x8*>(smem);
  const int row0 = w * 32 + l15;
  f32x4 acc[2];
  acc[0] = (f32x4){0.f, 0.f, 0.f, 0.f};
  acc[1] = (f32x4){0.f, 0.f, 0.f, 0.f};
#pragma unroll 4
  for (int kt = 0; kt < 64; ++kt) {
    bf16x8 af0 = *reinterpret_cast<const bf16x8*>(h1f + (size_t)row0 * Hn + kt * 32 + kq * 8);
    bf16x8 af1 = *reinterpret_cast<const bf16x8*>(h1f + (size_t)(row0 + 16) * Hn + kt * 32 + kq * 8);
    bf16x8 bf = wlds[kt * 64 + l];
    acc[0] = __builtin_amdgcn_mfma_f32_16x16x32_bf16(af0, bf, acc[0], 0, 0, 0);
    acc[1] = __builtin_amdgcn_mfma_f32_16x16x32_bf16(af1, bf, acc[1], 0, 0, 0);
  }
  const int col = g * 16 + l15;
  const float bb = b1[col];
#pragma unroll
  for (int mt = 0; mt < 2; ++mt)
#pragma unroll
    for (int r = 0; r < 4; ++r) {
      float v = fmaxf(acc[mt][r] + bb, 0.f);
      const int row = w * 32 + mt * 16 + kq * 4 + r;
      a1[(size_t)row * En + col] = f2b(v);
    }
}

__global__ __launch_bounds__(256) void head2(const uint4* __restrict__ imgW2,
                                             const unsigned short* __restrict__ a1,
                                             const float* __restrict__ b2,
                                             float* __restrict__ out) {
  __shared__ uint4 smem[4096];
  const int tid = threadIdx.x;
  const int w = tid >> 6, l = tid & 63, l15 = l & 15, kq = l >> 4;
  const int g = blockIdx.x;
  const uint4* src = imgW2 + (size_t)g * 4096;
  for (int i = tid; i < 4096; i += 256) smem[i] = src[i];
  __syncthreads();
  const bf16x8* wlds = reinterpret_cast<const bf16x8*>(smem);
  const int row0 = w * 32 + l15;
  f32x4 acc[2][4];
#pragma unroll
  for (int mt = 0; mt < 2; ++mt)
#pragma unroll
    for (int ct = 0; ct < 4; ++ct) acc[mt][ct] = (f32x4){0.f, 0.f, 0.f, 0.f};
#pragma unroll
  for (int kt = 0; kt < 16; ++kt) {
    bf16x8 af0 = *reinterpret_cast<const bf16x8*>(a1 + (size_t)row0 * En + kt * 32 + kq * 8);
    bf16x8 af1 = *reinterpret_cast<const bf16x8*>(a1 + (size_t)(row0 + 16) * En + kt * 32 + kq * 8);
#pragma unroll
    for (int ct = 0; ct < 4; ++ct) {
      bf16x8 bf = wlds[(kt * 4 + ct) * 64 + l];
      acc[0][ct] = __builtin_amdgcn_mfma_f32_16x16x32_bf16(af0, bf, acc[0][ct], 0, 0, 0);
      acc[1][ct] = __builtin_amdgcn_mfma_f32_16x16x32_bf16(af1, bf, acc[1][ct], 0, 0, 0);
    }
  }
#pragma unroll
  for (int mt = 0; mt < 2; ++mt)
#pragma unroll
    for (int ct = 0; ct < 4; ++ct) {
      const int col = g * 64 + ct * 16 + l15;
      const float bb = b2[col];
#pragma unroll
      for (int r = 0; r < 4; ++r) {
        const int row = w * 32 + mt * 16 + kq * 4 + r;
        out[(size_t)row * Vn + col] = acc[mt][ct][r] + bb;
      }
    }
}

// ---------------- launch ----------------
extern "C" void kernel_launch(void* const* d_in, const int* in_sizes, int n_in,
                              void* d_out, int out_size, void* d_ws, size_t ws_size,
                              hipStream_t stream) {
  (void)in_sizes; (void)n_in; (void)out_size;
  const int* ids    = (const int*)d_in[0];
  const float* emb  = (const float*)d_in[1];
  const float* Wih0 = (const float*)d_in[2];
  const float* Whh0 = (const float*)d_in[3];
  const float* bih0 = (const float*)d_in[4];
  const float* bhh0 = (const float*)d_in[5];
  const float* Wih1 = (const float*)d_in[6];
  const float* Whh1 = (const float*)d_in[7];
  const float* bih1 = (const float*)d_in[8];
  const float* bhh1 = (const float*)d_in[9];
  const float* W1   = (const float*)d_in[10];
  const float* b1   = (const float*)d_in[11];
  const float* W2   = (const float*)d_in[12];
  const float* b2   = (const float*)d_in[13];
  float* out = (float*)d_out;

  char* ws = (char*)d_ws;
  size_t o = 0;
  auto alloc = [&](size_t bytes) -> char* {
    char* p = ws + o;
    o += (bytes + 255) & ~(size_t)255;
    return p;
  };
  uint32_t* flags = (uint32_t*)alloc(FLAG_WORDS * 4);
  float* bias0 = (float*)alloc(Hn * 4);
  float* bias1 = (float*)alloc(Hn * 4);
  unsigned short* h0ring = (unsigned short*)alloc((size_t)R0 * HSLOT * 2);
  unsigned short* h1ring = (unsigned short*)alloc((size_t)R1 * HSLOT * 2);
  float* pbufA = (float*)alloc(16ull * 5 * 16384 * 4);
  float* pbufB = (float*)alloc(16ull * 8 * 16384 * 4);
  unsigned short* a1 = (unsigned short*)alloc((size_t)Bn * En * 2);
  uint4* imgWih0 = (uint4*)alloc(16ull * 8192 * 16);
  uint4* imgWhh0 = (uint4*)alloc(64ull * 8192 * 16);
  uint4* imgWih1 = (uint4*)alloc(64ull * 8192 * 16);
  uint4* imgWhh1 = (uint4*)alloc(64ull * 8192 * 16);
  uint4* imgW1 = (uint4*)alloc(32ull * 4096 * 16);
  uint4* imgW2 = (uint4*)alloc(500ull * 4096 * 16);
  uint4* xall  = (uint4*)alloc((size_t)Tn * Bn * En * 2);
  if (o > ws_size) return;  // fail visibly, no OOB

  zero3<<<512, 256, 0, stream>>>(flags, FLAG_WORDS,
                                 (uint32_t*)(h0ring + (size_t)(R0 - 1) * HSLOT), 131072,
                                 (uint32_t*)(h1ring + (size_t)(R1 - 1) * HSLOT), 131072);
  pack_bias<<<8, 256, 0, stream>>>(bih0, bhh0, bih1, bhh1, bias0, bias1);
  pack_seg<<<512, 256, 0, stream>>>(Wih0, 512, 1, imgWih0);
  pack_seg<<<2048, 256, 0, stream>>>(Whh0, 2048, 4, imgWhh0);
  pack_seg<<<2048, 256, 0, stream>>>(Wih1, 2048, 4, imgWih1);
  pack_seg<<<2048, 256, 0, stream>>>(Whh1, 2048, 4, imgWhh1);
  pack_imgW1<<<512, 256, 0, stream>>>(W1, imgW1);
  pack_imgW2<<<8000, 256, 0, stream>>>(W2, imgW2);
  gather_x<<<16384, 256, 0, stream>>>(ids, emb, xall);

  rnn_persist<<<208, 256, 0, stream>>>(imgWih0, imgWhh0, imgWih1, imgWhh1,
                                       (const unsigned short*)xall, h0ring, h1ring,
                                       pbufA, pbufB, bias0, bias1, flags);

  head1<<<32, 256, 0, stream>>>(imgW1, h1ring + (size_t)(511 % R1) * HSLOT, b1, a1);
  head2<<<500, 256, 0, stream>>>(imgW2, a1, b2, out);
}

// Round 15
// 13968.684 us; speedup vs baseline: 2.5745x; 2.0021x over previous
//
#include <hip/hip_runtime.h>
#include <hip/hip_bf16.h>
#include <stdint.h>

// Problem dims
#define Bn 128
#define Tn 512
#define En 512
#define Hn 2048
#define Vn 32000
#define R0 8
#define R1 4
#define HSLOT (Bn*Hn)

// flags: reps r*1024 (+0 fA0[16], +64 fB0[16]); FPA/FPB private lines
#define NREP 8
#define FPA 8192       // + (g*8+s)*16
#define FPB 10240      // + (g*8+s)*16
#define FLAG_WORDS 16384
#define BAILLIM 16384

typedef float f32x4 __attribute__((ext_vector_type(4)));
typedef short bf16x8 __attribute__((ext_vector_type(8)));
typedef unsigned int u32x4 __attribute__((ext_vector_type(4)));
typedef unsigned long long u64;

__device__ __forceinline__ unsigned short f2b(float f) {
  uint32_t x = __builtin_bit_cast(uint32_t, f);
  uint32_t r = x + 0x7FFFu + ((x >> 16) & 1u);
  return (unsigned short)(r >> 16);
}
__device__ __forceinline__ uint32_t pk2(float a, float b) {
  return (uint32_t)f2b(a) | ((uint32_t)f2b(b) << 16);
}
__device__ __forceinline__ float blo(uint32_t u) {
  return __builtin_bit_cast(float, (uint32_t)(u << 16));
}
__device__ __forceinline__ float bhi(uint32_t u) {
  return __builtin_bit_cast(float, (uint32_t)(u & 0xFFFF0000u));
}

// MALL ops (r2-r9 proven)
__device__ __forceinline__ uint32_t ldf(const uint32_t* p) {
  return __hip_atomic_load(p, __ATOMIC_RELAXED, __HIP_MEMORY_SCOPE_AGENT);
}
__device__ __forceinline__ void stf(uint32_t* p, uint32_t v) {
  __hip_atomic_store(p, v, __ATOMIC_RELAXED, __HIP_MEMORY_SCOPE_AGENT);
}
__device__ __forceinline__ void st64(u64* p, u64 v) {
  __hip_atomic_store(p, v, __ATOMIC_RELAXED, __HIP_MEMORY_SCOPE_AGENT);
}
__device__ __forceinline__ void drain_then_sync() {
  asm volatile("s_waitcnt vmcnt(0)" ::: "memory");
  __syncthreads();
}

// 16-deep MALL-coherent loads (sc0 sc1 — r7-proven) for h reads: 8 kt-tiles x 2 rows
#define LD16_MALL(PA, PB) \
  asm volatile( \
      "global_load_dwordx4 %[t0], %[a], off sc0 sc1\n\t" \
      "global_load_dwordx4 %[t1], %[a], off offset:64 sc0 sc1\n\t" \
      "global_load_dwordx4 %[t2], %[a], off offset:128 sc0 sc1\n\t" \
      "global_load_dwordx4 %[t3], %[a], off offset:192 sc0 sc1\n\t" \
      "global_load_dwordx4 %[t4], %[a], off offset:256 sc0 sc1\n\t" \
      "global_load_dwordx4 %[t5], %[a], off offset:320 sc0 sc1\n\t" \
      "global_load_dwordx4 %[t6], %[a], off offset:384 sc0 sc1\n\t" \
      "global_load_dwordx4 %[t7], %[a], off offset:448 sc0 sc1\n\t" \
      "global_load_dwordx4 %[t8], %[b], off sc0 sc1\n\t" \
      "global_load_dwordx4 %[t9], %[b], off offset:64 sc0 sc1\n\t" \
      "global_load_dwordx4 %[ta], %[b], off offset:128 sc0 sc1\n\t" \
      "global_load_dwordx4 %[tb], %[b], off offset:192 sc0 sc1\n\t" \
      "global_load_dwordx4 %[tc], %[b], off offset:256 sc0 sc1\n\t" \
      "global_load_dwordx4 %[td], %[b], off offset:320 sc0 sc1\n\t" \
      "global_load_dwordx4 %[te], %[b], off offset:384 sc0 sc1\n\t" \
      "global_load_dwordx4 %[tf], %[b], off offset:448 sc0 sc1\n\t" \
      "s_waitcnt vmcnt(0)" \
      : [t0]"=&v"(v0), [t1]"=&v"(v1), [t2]"=&v"(v2), [t3]"=&v"(v3), \
        [t4]"=&v"(v4), [t5]"=&v"(v5), [t6]"=&v"(v6), [t7]"=&v"(v7), \
        [t8]"=&v"(v8), [t9]"=&v"(v9), [ta]"=&v"(va), [tb]"=&v"(vb), \
        [tc]"=&v"(vc), [td]"=&v"(vd), [te]"=&v"(ve), [tf]"=&v"(vf) \
      : [a]"v"(PA), [b]"v"(PB) : "memory"); \
  __builtin_amdgcn_sched_barrier(0)

// ---------------- init / pack kernels ----------------

__global__ void zero3(uint32_t* a, int na, uint32_t* b, int nb, uint32_t* c, int nc) {
  int i = blockIdx.x * 256 + threadIdx.x;
  if (i < na) a[i] = 0u;
  if (i < nb) b[i] = 0u;
  if (i < nc) c[i] = 0u;
}

__global__ void pack_bias(const float* bih0, const float* bhh0,
                          const float* bih1, const float* bhh1,
                          float* bias0, float* bias1) {
  int i = blockIdx.x * 256 + threadIdx.x;
  bias0[i] = bih0[i] + bhh0[i];
  bias1[i] = bih1[i] + bhh1[i];
}

// 16 groups x 128 cols, nseg K-segments of 512. packet p=(kt*8+ct)*64+l within
// (g,seg) slice of 8192 packets. lane l elem j: src[col=g*128+ct*16+(l&15)]
// [k = seg*512 + kt*32 + (l>>4)*8 + j], src row-major [2048 x Ksrc].
__global__ void pack_seg(const float* __restrict__ src, int Ksrc, int nseg,
                         uint4* __restrict__ img) {
  int tid = blockIdx.x * 256 + threadIdx.x;
  int per = nseg * 8192;
  int g = tid / per, r1 = tid - g * per;
  int seg = r1 >> 13, p = r1 & 8191;
  int kt = p >> 9, ct = (p >> 6) & 7, l = p & 63;
  int col = g * 128 + ct * 16 + (l & 15);
  int k = seg * 512 + kt * 32 + (l >> 4) * 8;
  const float* s = src + (size_t)col * Ksrc + k;
  unsigned short o[8];
#pragma unroll
  for (int j = 0; j < 8; ++j) o[j] = f2b(s[j]);
  img[tid] = *reinterpret_cast<uint4*>(o);
}

__global__ void pack_imgW1(const float* __restrict__ W1, uint4* __restrict__ img) {
  int tid = blockIdx.x * 256 + threadIdx.x;
  int grp = tid >> 12;
  int p = tid & 4095;
  int l = p & 63;
  int kt = p >> 6;
  int col = grp * 16 + (l & 15);
  int k0 = kt * 32 + (l >> 4) * 8;
  const float* src = W1 + (size_t)col * Hn + k0;
  unsigned short o[8];
#pragma unroll
  for (int j = 0; j < 8; ++j) o[j] = f2b(src[j]);
  img[tid] = *reinterpret_cast<uint4*>(o);
}

__global__ void pack_imgW2(const float* __restrict__ W2, uint4* __restrict__ img) {
  int tid = blockIdx.x * 256 + threadIdx.x;
  int grp = tid >> 12;
  int p = tid & 4095;
  int l = p & 63;
  int ckt = p >> 6;
  int ct = ckt & 3, kt = ckt >> 2;
  int col = grp * 64 + ct * 16 + (l & 15);
  int k0 = kt * 32 + (l >> 4) * 8;
  const float* src = W2 + (size_t)col * En + k0;
  unsigned short o[8];
#pragma unroll
  for (int j = 0; j < 8; ++j) o[j] = f2b(src[j]);
  img[tid] = *reinterpret_cast<uint4*>(o);
}

__global__ void gather_x(const int* __restrict__ ids, const float* __restrict__ emb,
                         uint4* __restrict__ xall) {
  int tid = blockIdx.x * 256 + threadIdx.x;
  int t = tid >> 13;
  int r = tid & 8191;
  int b = r >> 6;
  int e8 = r & 63;
  int id = ids[b * Tn + t];
  const float* src = emb + (size_t)id * En + e8 * 8;
  unsigned short o[8];
#pragma unroll
  for (int j = 0; j < 8; ++j) o[j] = f2b(src[j]);
  xall[tid] = *reinterpret_cast<uint4*>(o);
}

// ---------------- persistent RNN v17: bf16 partials via PROVEN atomic stores ----
// v16's asm `global_store_dwordx4 sc0 sc1` stores were never visible cross-XCD
// (output collapsed to exact-zero => reducers read poison ~0). v17 keeps the bf16
// format + layout but stores partials with __hip_atomic_store u64 (agent relaxed)
// — the ONLY store mechanism proven cross-XCD-visible in this loop (r2-r14).
// Thread (w,l) chunk-pair c2: 8 bf16 (16B) at halves w*4096 + c2*512 + l*8,
// written as two contiguous st64s. Reads: r7-proven sc0 sc1 asm loads.

#define MFB8(KT, A0, A1) do { \
    bf16x8 bw_; \
    _Pragma("unroll") \
    for (int ct_ = 0; ct_ < 8; ++ct_) { \
      bw_ = wlds[((KT) * 8 + ct_) * 64 + l]; \
      acc[0][ct_] = __builtin_amdgcn_mfma_f32_16x16x32_bf16(A0, bw_, acc[0][ct_], 0, 0, 0); \
      acc[1][ct_] = __builtin_amdgcn_mfma_f32_16x16x32_bf16(A1, bw_, acc[1][ct_], 0, 0, 0); \
    } \
  } while (0)

// K=512 slice from BASE (row-major, stride STRIDE elements), MALL-coherent
#define KLOOP512(BASE, STRIDE) do { \
    const unsigned short* pr0_ = (BASE) + (size_t)row0 * (STRIDE) + kq * 8; \
    const unsigned short* pr1_ = pr0_ + (size_t)16 * (STRIDE); \
    _Pragma("unroll") \
    for (int b_ = 0; b_ < 2; ++b_) { \
      const unsigned short* pa_ = pr0_ + b_ * 256; \
      const unsigned short* pb_ = pr1_ + b_ * 256; \
      bf16x8 v0,v1,v2,v3,v4,v5,v6,v7,v8,v9,va,vb,vc,vd,ve,vf; \
      LD16_MALL(pa_, pb_); \
      const int kb_ = b_ * 8; \
      MFB8(kb_+0, v0, v8); MFB8(kb_+1, v1, v9); MFB8(kb_+2, v2, va); MFB8(kb_+3, v3, vb); \
      MFB8(kb_+4, v4, vc); MFB8(kb_+5, v5, vd); MFB8(kb_+6, v6, ve); MFB8(kb_+7, v7, vf); \
    } \
  } while (0)

// store bf16 partial slot: chunk-pair c2 -> 16B = two contiguous atomic st64s
#define ST_PARTIAL(DST) do { \
    u64* d_ = (u64*)((DST) + (size_t)w * 4096 + (size_t)l * 8); \
    _Pragma("unroll") \
    for (int c2_ = 0; c2_ < 8; ++c2_) { \
      const int ca_ = 2 * c2_, cb_ = 2 * c2_ + 1; \
      f32x4 xa_ = acc[ca_ >> 3][ca_ & 7], xb_ = acc[cb_ >> 3][cb_ & 7]; \
      u64 q0_ = (u64)pk2(xa_[0], xa_[1]) | ((u64)pk2(xa_[2], xa_[3]) << 32); \
      u64 q1_ = (u64)pk2(xb_[0], xb_[1]) | ((u64)pk2(xb_[2], xb_[3]) << 32); \
      st64(d_ + (size_t)c2_ * 128, q0_); \
      st64(d_ + (size_t)c2_ * 128 + 1, q1_); \
    } \
  } while (0)

// load+unpack+add bf16 partial slot (8 x dwordx4, 2 bases x 4 imm offsets; proven loads)
#define ADD_PARTIAL(SRC) do { \
    const unsigned short* b0_ = (SRC) + (size_t)w * 4096 + (size_t)l * 8; \
    const unsigned short* b1_ = b0_ + 2048; \
    u32x4 r0_, r1_, r2_, r3_, r4_, r5_, r6_, r7_; \
    asm volatile( \
        "global_load_dwordx4 %[t0], %[a], off sc0 sc1\n\t" \
        "global_load_dwordx4 %[t1], %[a], off offset:1024 sc0 sc1\n\t" \
        "global_load_dwordx4 %[t2], %[a], off offset:2048 sc0 sc1\n\t" \
        "global_load_dwordx4 %[t3], %[a], off offset:3072 sc0 sc1\n\t" \
        "global_load_dwordx4 %[t4], %[b], off sc0 sc1\n\t" \
        "global_load_dwordx4 %[t5], %[b], off offset:1024 sc0 sc1\n\t" \
        "global_load_dwordx4 %[t6], %[b], off offset:2048 sc0 sc1\n\t" \
        "global_load_dwordx4 %[t7], %[b], off offset:3072 sc0 sc1\n\t" \
        "s_waitcnt vmcnt(0)" \
        : [t0]"=&v"(r0_), [t1]"=&v"(r1_), [t2]"=&v"(r2_), [t3]"=&v"(r3_), \
          [t4]"=&v"(r4_), [t5]"=&v"(r5_), [t6]"=&v"(r6_), [t7]"=&v"(r7_) \
        : [a]"v"(b0_), [b]"v"(b1_) : "memory"); \
    __builtin_amdgcn_sched_barrier(0); \
    u32x4 rr_[8] = {r0_, r1_, r2_, r3_, r4_, r5_, r6_, r7_}; \
    _Pragma("unroll") \
    for (int c2_ = 0; c2_ < 8; ++c2_) { \
      const int ca_ = 2 * c2_, cb_ = 2 * c2_ + 1; \
      f32x4* pa_ = &acc[ca_ >> 3][ca_ & 7]; \
      f32x4* pb_ = &acc[cb_ >> 3][cb_ & 7]; \
      (*pa_)[0] += blo(rr_[c2_][0]); (*pa_)[1] += bhi(rr_[c2_][0]); \
      (*pa_)[2] += blo(rr_[c2_][1]); (*pa_)[3] += bhi(rr_[c2_][1]); \
      (*pb_)[0] += blo(rr_[c2_][2]); (*pb_)[1] += bhi(rr_[c2_][2]); \
      (*pb_)[2] += blo(rr_[c2_][3]); (*pb_)[3] += bhi(rr_[c2_][3]); \
    } \
  } while (0)

__global__ __launch_bounds__(256, 1) void rnn_persist(
    const uint4* __restrict__ imgWih0, const uint4* __restrict__ imgWhh0,
    const uint4* __restrict__ imgWih1, const uint4* __restrict__ imgWhh1,
    const unsigned short* __restrict__ xall,
    unsigned short* __restrict__ h0ring, unsigned short* __restrict__ h1ring,
    unsigned short* __restrict__ pbufA, unsigned short* __restrict__ pbufB,
    const float* __restrict__ bias0, const float* __restrict__ bias1,
    uint32_t* flags) {
  __shared__ uint4 smem[8192];  // 128 KiB -> 1 block/CU, 208 blocks all resident
  const int tid = threadIdx.x;
  const int w = tid >> 6, l = tid & 63, l15 = l & 15, kq = l >> 4;
  const int blk = blockIdx.x;
  const bool roleA = (blk < 80);
  const int g = roleA ? (blk / 5) : ((blk - 80) >> 3);
  const int s = roleA ? (blk % 5) : ((blk - 80) & 7);
  const int myrep = blk & (NREP - 1);
  const uint32_t* fA0r = flags + (size_t)myrep * 1024;
  const uint32_t* fB0r = flags + (size_t)myrep * 1024 + 64;
  const int colbase = g * 128;

  {  // stage weights (128 KiB slice)
    const uint4* wsrc;
    if (roleA) wsrc = (s == 0) ? (imgWih0 + (size_t)g * 8192)
                               : (imgWhh0 + (size_t)(g * 4 + s - 1) * 8192);
    else       wsrc = (s < 4)  ? (imgWih1 + (size_t)(g * 4 + s) * 8192)
                               : (imgWhh1 + (size_t)(g * 4 + s - 4) * 8192);
    for (int i = tid; i < 8192; i += 256) smem[i] = wsrc[i];
  }
  __syncthreads();
  const bf16x8* wlds = reinterpret_cast<const bf16x8*>(smem);
  const int row0 = w * 32 + l15;

  for (int t = 0; t < Tn; ++t) {
    f32x4 acc[2][8];
#pragma unroll
    for (int mt = 0; mt < 2; ++mt)
#pragma unroll
      for (int ct = 0; ct < 8; ++ct) acc[mt][ct] = (f32x4){0.f, 0.f, 0.f, 0.f};

    if (roleA && s == 0) {
      // x-partial producer
      if (t >= 1) {
        int guard = 0;
        for (;;) {
          int ok = 1;
          if (tid == 0) ok = ((int)ldf(&fA0r[g]) >= t);
          if (++guard > BAILLIM) ok = 1;
          if (__syncthreads_and(ok)) break;
          __builtin_amdgcn_s_sleep(1);
        }
      }
      const unsigned short* xt = xall + (size_t)t * (Bn * En);
#pragma unroll 2
      for (int kt = 0; kt < 16; ++kt) {
        bf16x8 a0 = *reinterpret_cast<const bf16x8*>(xt + (size_t)row0 * En + kt * 32 + kq * 8);
        bf16x8 a1 = *reinterpret_cast<const bf16x8*>(xt + (size_t)(row0 + 16) * En + kt * 32 + kq * 8);
        MFB8(kt, a0, a1);
      }
      ST_PARTIAL(pbufA + (size_t)(g * 5 + 0) * 16384);
      drain_then_sync();
      if (tid == 0) stf(flags + FPA + (size_t)(g * 8 + 0) * 16, (uint32_t)(t + 1));
    } else if (roleA && s != 1) {
      // Whh0 partial, slice (s-1)*512
      {
        int guard = 0;
        for (;;) {
          int ok = 1;
          if (tid < 16) ok = ((int)ldf(&fA0r[tid]) >= t);
          if (++guard > BAILLIM) ok = 1;
          if (__syncthreads_and(ok)) break;
          __builtin_amdgcn_s_sleep(1);
        }
      }
      const unsigned short* hp = h0ring + (size_t)((t + R0 - 1) % R0) * HSLOT + (s - 1) * 512;
      KLOOP512(hp, Hn);
      ST_PARTIAL(pbufA + (size_t)(g * 5 + s) * 16384);
      drain_then_sync();
      if (tid == 0) stf(flags + FPA + (size_t)(g * 8 + s) * 16, (uint32_t)(t + 1));
    } else if (roleA) {
      // s==1: reducer-A (own slice k in [0,512))
      {
        int guard = 0;
        const bool ring = (t >= R0);
        for (;;) {
          int ok = 1;
          if (tid < 16) ok = ((int)ldf(&fA0r[tid]) >= t);
          else if (ring && tid >= 32 && tid < 48)
            ok = ((int)ldf(&fB0r[tid - 32]) >= t - R0 + 1);
          if (++guard > BAILLIM) ok = 1;
          if (__syncthreads_and(ok)) break;
          __builtin_amdgcn_s_sleep(1);
        }
      }
      const unsigned short* hp = h0ring + (size_t)((t + R0 - 1) % R0) * HSLOT;
      KLOOP512(hp, Hn);
      {
        int guard = 0;
        for (;;) {
          int ok = 1;
          if (tid < 4) {
            const int js[4] = {0, 2, 3, 4};
            ok = ((int)ldf(flags + FPA + (size_t)(g * 8 + js[tid]) * 16) >= t + 1);
          }
          if (++guard > BAILLIM) ok = 1;
          if (__syncthreads_and(ok)) break;
          __builtin_amdgcn_s_sleep(1);
        }
      }
      ADD_PARTIAL(pbufA + (size_t)(g * 5 + 0) * 16384);
      ADD_PARTIAL(pbufA + (size_t)(g * 5 + 2) * 16384);
      ADD_PARTIAL(pbufA + (size_t)(g * 5 + 3) * 16384);
      ADD_PARTIAL(pbufA + (size_t)(g * 5 + 4) * 16384);
      unsigned short* hdst = h0ring + (size_t)(t % R0) * HSLOT;
#pragma unroll
      for (int mt = 0; mt < 2; ++mt) {
#pragma unroll
        for (int ct = 0; ct < 8; ++ct) {
          const int col = colbase + ct * 16 + l15;
          const float bb = bias0[col];
#pragma unroll
          for (int r = 0; r < 4; ++r) {
            float v = tanhf(acc[mt][ct][r] + bb);
            int bo = f2b(v);
            int p2 = __shfl_down(bo, 1);
            uint32_t pair = (uint32_t)(unsigned short)bo | ((uint32_t)(unsigned short)p2 << 16);
            uint32_t hi = __shfl_down((int)pair, 2);
            if ((l15 & 3) == 0) {
              const int row = w * 32 + mt * 16 + kq * 4 + r;
              u64 qv = (u64)pair | ((u64)hi << 32);
              st64((u64*)(hdst + (size_t)row * Hn + col), qv);
            }
          }
        }
      }
      drain_then_sync();
      if (tid < NREP) stf(flags + (size_t)tid * 1024 + g, (uint32_t)(t + 1));
    } else if (s < 4) {
      // roleB Wih1 partial on h0[t]
      {
        int guard = 0;
        for (;;) {
          int ok = 1;
          if (tid < 16) ok = ((int)ldf(&fA0r[tid]) >= t + 1);
          else if (tid == 16) ok = ((int)ldf(&fB0r[g]) >= t);  // race-fix
          if (++guard > BAILLIM) ok = 1;
          if (__syncthreads_and(ok)) break;
          __builtin_amdgcn_s_sleep(1);
        }
      }
      const unsigned short* hp = h0ring + (size_t)(t % R0) * HSLOT + s * 512;
      KLOOP512(hp, Hn);
      ST_PARTIAL(pbufB + (size_t)(g * 8 + s) * 16384);
      drain_then_sync();
      if (tid == 0) stf(flags + FPB + (size_t)(g * 8 + s) * 16, (uint32_t)(t + 1));
    } else if (s != 4) {
      // roleB Whh1 partial on h1[t-1], slice (s-4)*512
      {
        int guard = 0;
        for (;;) {
          int ok = 1;
          if (tid < 16) ok = ((int)ldf(&fB0r[tid]) >= t);
          if (++guard > BAILLIM) ok = 1;
          if (__syncthreads_and(ok)) break;
          __builtin_amdgcn_s_sleep(1);
        }
      }
      const unsigned short* hp = h1ring + (size_t)((t + R1 - 1) % R1) * HSLOT + (s - 4) * 512;
      KLOOP512(hp, Hn);
      ST_PARTIAL(pbufB + (size_t)(g * 8 + s) * 16384);
      drain_then_sync();
      if (tid == 0) stf(flags + FPB + (size_t)(g * 8 + s) * 16, (uint32_t)(t + 1));
    } else {
      // s==4: reducer-B (own: Whh1 slice 0 on h1[t-1])
      {
        int guard = 0;
        for (;;) {
          int ok = 1;
          if (tid < 16) ok = ((int)ldf(&fB0r[tid]) >= t);
          if (++guard > BAILLIM) ok = 1;
          if (__syncthreads_and(ok)) break;
          __builtin_amdgcn_s_sleep(1);
        }
      }
      const unsigned short* hp = h1ring + (size_t)((t + R1 - 1) % R1) * HSLOT;
      KLOOP512(hp, Hn);
      {
        int guard = 0;
        for (;;) {
          int ok = 1;
          if (tid < 7) {
            const int js[7] = {0, 1, 2, 3, 5, 6, 7};
            ok = ((int)ldf(flags + FPB + (size_t)(g * 8 + js[tid]) * 16) >= t + 1);
          }
          if (++guard > BAILLIM) ok = 1;
          if (__syncthreads_and(ok)) break;
          __builtin_amdgcn_s_sleep(1);
        }
      }
      ADD_PARTIAL(pbufB + (size_t)(g * 8 + 0) * 16384);
      ADD_PARTIAL(pbufB + (size_t)(g * 8 + 1) * 16384);
      ADD_PARTIAL(pbufB + (size_t)(g * 8 + 2) * 16384);
      ADD_PARTIAL(pbufB + (size_t)(g * 8 + 3) * 16384);
      ADD_PARTIAL(pbufB + (size_t)(g * 8 + 5) * 16384);
      ADD_PARTIAL(pbufB + (size_t)(g * 8 + 6) * 16384);
      ADD_PARTIAL(pbufB + (size_t)(g * 8 + 7) * 16384);
      unsigned short* hdst = h1ring + (size_t)(t % R1) * HSLOT;
#pragma unroll
      for (int mt = 0; mt < 2; ++mt) {
#pragma unroll
        for (int ct = 0; ct < 8; ++ct) {
          const int col = colbase + ct * 16 + l15;
          const float bb = bias1[col];
#pragma unroll
          for (int r = 0; r < 4; ++r) {
            float v = tanhf(acc[mt][ct][r] + bb);
            int bo = f2b(v);
            int p2 = __shfl_down(bo, 1);
            uint32_t pair = (uint32_t)(unsigned short)bo | ((uint32_t)(unsigned short)p2 << 16);
            uint32_t hi = __shfl_down((int)pair, 2);
            if ((l15 & 3) == 0) {
              const int row = w * 32 + mt * 16 + kq * 4 + r;
              u64 qv = (u64)pair | ((u64)hi << 32);
              st64((u64*)(hdst + (size_t)row * Hn + col), qv);
            }
          }
        }
      }
      drain_then_sync();
      if (tid < NREP) stf(flags + (size_t)tid * 1024 + 64 + g, (uint32_t)(t + 1));
    }
  }
}

// ---------------- head (proven) ----------------
__global__ __launch_bounds__(256) void head1(const uint4* __restrict__ imgW1,
                                             const unsigned short* __restrict__ h1f,
                                             const float* __restrict__ b1,
                                             unsigned short* __restrict__ a1) {
  __shared__ uint4 smem[4096];
  const int tid = threadIdx.x;
  const int w = tid >> 6, l = tid & 63, l15 = l & 15, kq = l >> 4;
  const int g = blockIdx.x;
  const uint4* src = imgW1 + (size_t)g * 4096;
  for (int i = tid; i < 4096; i += 256) smem[i] = src[i];
  __syncthreads();
  const bf16x8* wlds = reinterpret_cast<const bf16x8*>(smem);
  const int row0 = w * 32 + l15;
  f32x4 acc[2];
  acc[0] = (f32x4){0.f, 0.f, 0.f, 0.f};
  acc[1] = (f32x4){0.f, 0.f, 0.f, 0.f};
#pragma unroll 4
  for (int kt = 0; kt < 64; ++kt) {
    bf16x8 af0 = *reinterpret_cast<const bf16x8*>(h1f + (size_t)row0 * Hn + kt * 32 + kq * 8);
    bf16x8 af1 = *reinterpret_cast<const bf16x8*>(h1f + (size_t)(row0 + 16) * Hn + kt * 32 + kq * 8);
    bf16x8 bf = wlds[kt * 64 + l];
    acc[0] = __builtin_amdgcn_mfma_f32_16x16x32_bf16(af0, bf, acc[0], 0, 0, 0);
    acc[1] = __builtin_amdgcn_mfma_f32_16x16x32_bf16(af1, bf, acc[1], 0, 0, 0);
  }
  const int col = g * 16 + l15;
  const float bb = b1[col];
#pragma unroll
  for (int mt = 0; mt < 2; ++mt)
#pragma unroll
    for (int r = 0; r < 4; ++r) {
      float v = fmaxf(acc[mt][r] + bb, 0.f);
      const int row = w * 32 + mt * 16 + kq * 4 + r;
      a1[(size_t)row * En + col] = f2b(v);
    }
}

__global__ __launch_bounds__(256) void head2(const uint4* __restrict__ imgW2,
                                             const unsigned short* __restrict__ a1,
                                             const float* __restrict__ b2,
                                             float* __restrict__ out) {
  __shared__ uint4 smem[4096];
  const int tid = threadIdx.x;
  const int w = tid >> 6, l = tid & 63, l15 = l & 15, kq = l >> 4;
  const int g = blockIdx.x;
  const uint4* src = imgW2 + (size_t)g * 4096;
  for (int i = tid; i < 4096; i += 256) smem[i] = src[i];
  __syncthreads();
  const bf16x8* wlds = reinterpret_cast<const bf16x8*>(smem);
  const int row0 = w * 32 + l15;
  f32x4 acc[2][4];
#pragma unroll
  for (int mt = 0; mt < 2; ++mt)
#pragma unroll
    for (int ct = 0; ct < 4; ++ct) acc[mt][ct] = (f32x4){0.f, 0.f, 0.f, 0.f};
#pragma unroll
  for (int kt = 0; kt < 16; ++kt) {
    bf16x8 af0 = *reinterpret_cast<const bf16x8*>(a1 + (size_t)row0 * En + kt * 32 + kq * 8);
    bf16x8 af1 = *reinterpret_cast<const bf16x8*>(a1 + (size_t)(row0 + 16) * En + kt * 32 + kq * 8);
#pragma unroll
    for (int ct = 0; ct < 4; ++ct) {
      bf16x8 bf = wlds[(kt * 4 + ct) * 64 + l];
      acc[0][ct] = __builtin_amdgcn_mfma_f32_16x16x32_bf16(af0, bf, acc[0][ct], 0, 0, 0);
      acc[1][ct] = __builtin_amdgcn_mfma_f32_16x16x32_bf16(af1, bf, acc[1][ct], 0, 0, 0);
    }
  }
#pragma unroll
  for (int mt = 0; mt < 2; ++mt)
#pragma unroll
    for (int ct = 0; ct < 4; ++ct) {
      const int col = g * 64 + ct * 16 + l15;
      const float bb = b2[col];
#pragma unroll
      for (int r = 0; r < 4; ++r) {
        const int row = w * 32 + mt * 16 + kq * 4 + r;
        out[(size_t)row * Vn + col] = acc[mt][ct][r] + bb;
      }
    }
}

// ---------------- launch ----------------
extern "C" void kernel_launch(void* const* d_in, const int* in_sizes, int n_in,
                              void* d_out, int out_size, void* d_ws, size_t ws_size,
                              hipStream_t stream) {
  (void)in_sizes; (void)n_in; (void)out_size;
  const int* ids    = (const int*)d_in[0];
  const float* emb  = (const float*)d_in[1];
  const float* Wih0 = (const float*)d_in[2];
  const float* Whh0 = (const float*)d_in[3];
  const float* bih0 = (const float*)d_in[4];
  const float* bhh0 = (const float*)d_in[5];
  const float* Wih1 = (const float*)d_in[6];
  const float* Whh1 = (const float*)d_in[7];
  const float* bih1 = (const float*)d_in[8];
  const float* bhh1 = (const float*)d_in[9];
  const float* W1   = (const float*)d_in[10];
  const float* b1   = (const float*)d_in[11];
  const float* W2   = (const float*)d_in[12];
  const float* b2   = (const float*)d_in[13];
  float* out = (float*)d_out;

  char* ws = (char*)d_ws;
  size_t o = 0;
  auto alloc = [&](size_t bytes) -> char* {
    char* p = ws + o;
    o += (bytes + 255) & ~(size_t)255;
    return p;
  };
  uint32_t* flags = (uint32_t*)alloc(FLAG_WORDS * 4);
  float* bias0 = (float*)alloc(Hn * 4);
  float* bias1 = (float*)alloc(Hn * 4);
  unsigned short* h0ring = (unsigned short*)alloc((size_t)R0 * HSLOT * 2);
  unsigned short* h1ring = (unsigned short*)alloc((size_t)R1 * HSLOT * 2);
  unsigned short* pbufA = (unsigned short*)alloc(16ull * 5 * 16384 * 2);
  unsigned short* pbufB = (unsigned short*)alloc(16ull * 8 * 16384 * 2);
  unsigned short* a1 = (unsigned short*)alloc((size_t)Bn * En * 2);
  uint4* imgWih0 = (uint4*)alloc(16ull * 8192 * 16);
  uint4* imgWhh0 = (uint4*)alloc(64ull * 8192 * 16);
  uint4* imgWih1 = (uint4*)alloc(64ull * 8192 * 16);
  uint4* imgWhh1 = (uint4*)alloc(64ull * 8192 * 16);
  uint4* imgW1 = (uint4*)alloc(32ull * 4096 * 16);
  uint4* imgW2 = (uint4*)alloc(500ull * 4096 * 16);
  uint4* xall  = (uint4*)alloc((size_t)Tn * Bn * En * 2);
  if (o > ws_size) return;  // fail visibly, no OOB

  zero3<<<512, 256, 0, stream>>>(flags, FLAG_WORDS,
                                 (uint32_t*)(h0ring + (size_t)(R0 - 1) * HSLOT), 131072,
                                 (uint32_t*)(h1ring + (size_t)(R1 - 1) * HSLOT), 131072);
  pack_bias<<<8, 256, 0, stream>>>(bih0, bhh0, bih1, bhh1, bias0, bias1);
  pack_seg<<<512, 256, 0, stream>>>(Wih0, 512, 1, imgWih0);
  pack_seg<<<2048, 256, 0, stream>>>(Whh0, 2048, 4, imgWhh0);
  pack_seg<<<2048, 256, 0, stream>>>(Wih1, 2048, 4, imgWih1);
  pack_seg<<<2048, 256, 0, stream>>>(Whh1, 2048, 4, imgWhh1);
  pack_imgW1<<<512, 256, 0, stream>>>(W1, imgW1);
  pack_imgW2<<<8000, 256, 0, stream>>>(W2, imgW2);
  gather_x<<<16384, 256, 0, stream>>>(ids, emb, xall);

  rnn_persist<<<208, 256, 0, stream>>>(imgWih0, imgWhh0, imgWih1, imgWhh1,
                                       (const unsigned short*)xall, h0ring, h1ring,
                                       pbufA, pbufB, bias0, bias1, flags);

  head1<<<32, 256, 0, stream>>>(imgW1, h1ring + (size_t)(511 % R1) * HSLOT, b1, a1);
  head2<<<500, 256, 0, stream>>>(imgW2, a1, b2, out);
}